// Round 3
// baseline (1598.564 us; speedup 1.0000x reference)
//
#include <hip/hip_runtime.h>
#include <hip/hip_bf16.h>

#define BB 2
#define NN 4096
#define DD 192
#define DI 384
#define DS 16
#define DTR 12
#define DC 4
#define DEPTH 4
#define NT (BB*NN)
#define NCH 64
#define CL 64
#define EPSF 1e-5f

// arena element offsets (u16 units)
#define OFF_X       0
#define OFF_PROJ_W  24576
#define OFF_PROJ_B  25152
#define OFF_LP_W    25344
#define OFF_LP_B    320256
#define OFF_NORM_W  321024
#define OFF_IN_W    321792
#define OFF_CONV_W  911616
#define OFF_CONV_B  917760
#define OFF_XPROJ_W 919296
#define OFF_DT_W    986880
#define OFF_DT_B    1005312
#define OFF_A_LOG   1006848
#define OFF_DP      1031424
#define OFF_OUT_W   1032960
#define OFF_NORMF_W 1327872
#define ARENA_TOTAL 1328064
#define ARENA_BYTES 2656160   // ARENA_TOTAL*2 + 32 pad (16B aligned)

typedef __hip_bfloat16 bf16_t;
typedef unsigned short u16;
typedef unsigned int u32;
typedef __attribute__((ext_vector_type(8))) unsigned short u16x8;

struct Ptrs { const void* p[16]; };

__device__ __forceinline__ float bf(u16 v){ return __uint_as_float(((u32)v)<<16); }
__device__ __forceinline__ u16 f2bf(float f){
  u32 b = __float_as_uint(f);
  return (u16)((b + 0x7FFFu + ((b>>16)&1u)) >> 16);
}

// ---------------- dtype detector: are inputs bf16(u16) or f32 storage?
__global__ __launch_bounds__(256) void k_detect(const u16* __restrict__ x, int* flag){
  __shared__ int cnt;
  if (threadIdx.x==0) cnt=0;
  __syncthreads();
  u32 v = x[2*threadIdx.x];          // even u16: bf16 value (bf16 storage) or f32 low-mantissa (f32 storage)
  int ex = (int)((v>>7)&0xFF);
  if (ex>=100 && ex<=140) atomicAdd(&cnt,1);
  __syncthreads();
  if (threadIdx.x==0) *flag = (cnt>128) ? 0 : 1;   // 0 = bf16 storage, 1 = f32 storage
}

// ---------------- canonicalize all inputs into bf16 arena
__global__ __launch_bounds__(256) void k_cvt(Ptrs ps, const int* __restrict__ flag, u16* __restrict__ arena){
  int e = blockIdx.x*256 + threadIdx.x;
  if (e >= ARENA_TOTAL) return;
  const void* sp; int off;
  if      (e < OFF_PROJ_W ){ sp=ps.p[0];  off=OFF_X; }
  else if (e < OFF_PROJ_B ){ sp=ps.p[1];  off=OFF_PROJ_W; }
  else if (e < OFF_LP_W   ){ sp=ps.p[2];  off=OFF_PROJ_B; }
  else if (e < OFF_LP_B   ){ sp=ps.p[3];  off=OFF_LP_W; }
  else if (e < OFF_NORM_W ){ sp=ps.p[4];  off=OFF_LP_B; }
  else if (e < OFF_IN_W   ){ sp=ps.p[5];  off=OFF_NORM_W; }
  else if (e < OFF_CONV_W ){ sp=ps.p[6];  off=OFF_IN_W; }
  else if (e < OFF_CONV_B ){ sp=ps.p[7];  off=OFF_CONV_W; }
  else if (e < OFF_XPROJ_W){ sp=ps.p[8];  off=OFF_CONV_B; }
  else if (e < OFF_DT_W   ){ sp=ps.p[9];  off=OFF_XPROJ_W; }
  else if (e < OFF_DT_B   ){ sp=ps.p[10]; off=OFF_DT_W; }
  else if (e < OFF_A_LOG  ){ sp=ps.p[11]; off=OFF_DT_B; }
  else if (e < OFF_DP     ){ sp=ps.p[12]; off=OFF_A_LOG; }
  else if (e < OFF_OUT_W  ){ sp=ps.p[13]; off=OFF_DP; }
  else if (e < OFF_NORMF_W){ sp=ps.p[14]; off=OFF_OUT_W; }
  else                     { sp=ps.p[15]; off=OFF_NORMF_W; }
  int k = e - off;
  if (*flag){
    u32 v = ((const u32*)sp)[k];
    arena[e] = (u16)((v + 0x7FFFu + ((v>>16)&1u)) >> 16);
  } else {
    arena[e] = ((const u16*)sp)[k];
  }
}

// ---------------- initial projection: seq[b,n,d] = sum_c x[b,c,n]*pw[d,c] + pb[d]
__global__ __launch_bounds__(256) void k_proj(const u16* __restrict__ x, const u16* __restrict__ pw,
                                              const u16* __restrict__ pb, float* __restrict__ seq){
  int idx = blockIdx.x*256 + threadIdx.x;
  if (idx >= NT*DD) return;
  int d = idx % DD; int bn = idx / DD; int b = bn >> 12; int n = bn & (NN-1);
  float acc = bf(pb[d]);
  acc += bf(x[(b*3+0)*NN + n]) * bf(pw[d*3+0]);
  acc += bf(x[(b*3+1)*NN + n]) * bf(pw[d*3+1]);
  acc += bf(x[(b*3+2)*NN + n]) * bf(pw[d*3+2]);
  seq[idx] = acc;
}

// ---------------- shift+concat + lp GEMM + bias + rmsnorm -> xn (f32)
__global__ __launch_bounds__(192) void k_lp_norm(const float* __restrict__ seq,
    const u16* __restrict__ lp_w, const u16* __restrict__ lp_b, const u16* __restrict__ norm_w,
    float* __restrict__ xn){
  const int d = threadIdx.x;
  const int n0 = blockIdx.x*4;
  __shared__ float comb[4][2*DD];
  __shared__ float wred[4][3];
  #pragma unroll
  for (int t=0;t<4;++t){
    int bn = n0+t;
    float cur = seq[bn*DD + d];
    float prev = ((bn & (NN-1))==0) ? 0.f : seq[(bn-1)*DD + d];
    comb[t][d] = cur;
    comb[t][DD+d] = cur - prev;
  }
  __syncthreads();
  float a0=0.f,a1=0.f,a2=0.f,a3=0.f;
  const u16* w = lp_w + d*(2*DD);
  for (int c=0;c<2*DD;c+=8){
    u16x8 wv = *(const u16x8*)(w+c);
    float xv[4][8];
    #pragma unroll
    for (int t=0;t<4;++t){
      *(float4*)&xv[t][0] = *(const float4*)&comb[t][c];
      *(float4*)&xv[t][4] = *(const float4*)&comb[t][c+4];
    }
    #pragma unroll
    for (int j=0;j<8;++j){
      float wf = bf(wv[j]);
      a0 += wf*xv[0][j];
      a1 += wf*xv[1][j];
      a2 += wf*xv[2][j];
      a3 += wf*xv[3][j];
    }
  }
  float bb = bf(lp_b[d]);
  a0+=bb; a1+=bb; a2+=bb; a3+=bb;
  float s0=a0*a0, s1=a1*a1, s2=a2*a2, s3=a3*a3;
  #pragma unroll
  for (int off=32; off>=1; off>>=1){
    s0 += __shfl_down(s0,off);
    s1 += __shfl_down(s1,off);
    s2 += __shfl_down(s2,off);
    s3 += __shfl_down(s3,off);
  }
  int lane = d & 63, wq = d >> 6;
  if (lane==0){ wred[0][wq]=s0; wred[1][wq]=s1; wred[2][wq]=s2; wred[3][wq]=s3; }
  __syncthreads();
  float nw = bf(norm_w[d]);
  float r0 = rsqrtf((wred[0][0]+wred[0][1]+wred[0][2])*(1.f/DD) + EPSF);
  float r1 = rsqrtf((wred[1][0]+wred[1][1]+wred[1][2])*(1.f/DD) + EPSF);
  float r2 = rsqrtf((wred[2][0]+wred[2][1]+wred[2][2])*(1.f/DD) + EPSF);
  float r3 = rsqrtf((wred[3][0]+wred[3][1]+wred[3][2])*(1.f/DD) + EPSF);
  xn[(n0+0)*DD+d] = a0*r0*nw;
  xn[(n0+1)*DD+d] = a1*r1*nw;
  xn[(n0+2)*DD+d] = a2*r2*nw;
  xn[(n0+3)*DD+d] = a3*r3*nw;
}

// ---------------- in_w GEMM: xz[b,n,e] = sum_d xn*in_w[e,d]; split xi_raw / z
__global__ __launch_bounds__(256) void k_inproj(const float* __restrict__ xn,
    const u16* __restrict__ in_w, float* __restrict__ xi_r, float* __restrict__ zz){
  const int tid = threadIdx.x;
  const int n0 = blockIdx.x*4;
  __shared__ float xs[4][DD];
  for (int k=tid; k<4*DD; k+=256) xs[k/DD][k%DD] = xn[(n0 + k/DD)*DD + (k%DD)];
  __syncthreads();
  float acc[3][4];
  #pragma unroll
  for (int r=0;r<3;++r)
    #pragma unroll
    for (int t=0;t<4;++t) acc[r][t]=0.f;
  const u16* w0 = in_w + (tid      )*DD;
  const u16* w1 = in_w + (tid + 256)*DD;
  const u16* w2 = in_w + (tid + 512)*DD;
  for (int c=0;c<DD;c+=8){
    u16x8 v0 = *(const u16x8*)(w0+c);
    u16x8 v1 = *(const u16x8*)(w1+c);
    u16x8 v2 = *(const u16x8*)(w2+c);
    float xv[4][8];
    #pragma unroll
    for (int t=0;t<4;++t){
      *(float4*)&xv[t][0] = *(const float4*)&xs[t][c];
      *(float4*)&xv[t][4] = *(const float4*)&xs[t][c+4];
    }
    #pragma unroll
    for (int j=0;j<8;++j){
      float f0=bf(v0[j]), f1=bf(v1[j]), f2=bf(v2[j]);
      #pragma unroll
      for (int t=0;t<4;++t){
        acc[0][t]+=f0*xv[t][j];
        acc[1][t]+=f1*xv[t][j];
        acc[2][t]+=f2*xv[t][j];
      }
    }
  }
  #pragma unroll
  for (int r=0;r<3;++r){
    int e = tid + 256*r;
    #pragma unroll
    for (int t=0;t<4;++t){
      int bn = n0+t;
      if (e < DI) xi_r[bn*DI + e] = acc[r][t];
      else        zz[bn*DI + e - DI] = acc[r][t];
    }
  }
}

// ---------------- causal conv(k=4) + silu + xproj(44) + dt softplus
__global__ __launch_bounds__(256) void k_conv_proj(const float* __restrict__ xi_r,
    const u16* __restrict__ conv_w, const u16* __restrict__ conv_b,
    const u16* __restrict__ xproj_w, const u16* __restrict__ dt_w, const u16* __restrict__ dt_b,
    float* __restrict__ xi, float* __restrict__ dt_o, float* __restrict__ Bm, float* __restrict__ Cm){
  const int tid = threadIdx.x;
  const int n0 = blockIdx.x*8;
  const int b = n0 >> 12;
  __shared__ float xr[11][DI];
  __shared__ float xs[8][DI];
  __shared__ float dbc_s[8][44];
  for (int k=tid;k<11*DI;k+=256){
    int r=k/DI, i=k-r*DI;
    int bn=n0-3+r;
    float v=0.f;
    if (bn>=0 && (bn>>12)==b) v = xi_r[bn*DI+i];
    xr[r][i]=v;
  }
  __syncthreads();
  for (int k=tid;k<8*DI;k+=256){
    int t=k/DI, i=k-t*DI;
    float acc = bf(conv_b[i]);
    #pragma unroll
    for (int q=0;q<4;++q) acc += xr[t+q][i]*bf(conv_w[i*4+q]);
    float v = acc/(1.f+expf(-acc));
    xs[t][i]=v;
    xi[(n0+t)*DI+i]=v;
  }
  __syncthreads();
  for (int k=tid;k<8*44;k+=256){
    int t=k/44, e=k-t*44;
    const u16* w = xproj_w + e*DI;
    float acc=0.f;
    for (int c=0;c<DI;c+=8){
      u16x8 wv=*(const u16x8*)(w+c);
      float xv[8];
      *(float4*)&xv[0] = *(const float4*)&xs[t][c];
      *(float4*)&xv[4] = *(const float4*)&xs[t][c+4];
      #pragma unroll
      for (int j=0;j<8;++j) acc += bf(wv[j])*xv[j];
    }
    dbc_s[t][e]=acc;
    int bn=n0+t;
    if (e>=DTR && e<DTR+DS) Bm[bn*DS + e-DTR]=acc;
    else if (e>=DTR+DS) Cm[bn*DS + e-DTR-DS]=acc;
  }
  __syncthreads();
  for (int k=tid;k<8*DI;k+=256){
    int t=k/DI, i=k-t*DI;
    float acc = bf(dt_b[i]);
    #pragma unroll
    for (int j=0;j<DTR;++j) acc += dbc_s[t][j]*bf(dt_w[i*DTR+j]);
    float sp = (acc>20.f)? acc : log1pf(expf(acc));
    dt_o[(n0+t)*DI+i]=sp;
  }
}

// ---------------- scan phase 1: per-chunk local scan -> P (decay product), Q (end state)
__global__ __launch_bounds__(256) void k_scan1(const float* __restrict__ dt,
    const float* __restrict__ xi, const float* __restrict__ Bm,
    const u16* __restrict__ A_log, float* __restrict__ P, float* __restrict__ Q){
  const int bid = blockIdx.x;
  const int ig = bid % (DI/16);
  const int ch = (bid/(DI/16)) % NCH;
  const int b  = bid/((DI/16)*NCH);
  const int tid = threadIdx.x;
  const int s = tid & 15, il = tid >> 4;
  const int i = ig*16 + il;
  const float Av = -expf(bf(A_log[i*DS + s]));
  __shared__ float dt_l[16][16], xi_l[16][16], bm_l[16][16];
  float Pv = 1.f, h = 0.f;
  const int n0 = ch*CL;
  for (int sub=0; sub<CL/16; ++sub){
    int n = n0 + sub*16 + il;
    dt_l[il][s] = dt[(b*NN + n)*DI + ig*16 + s];
    xi_l[il][s] = xi[(b*NN + n)*DI + ig*16 + s];
    bm_l[il][s] = Bm[(b*NN + n)*DS + s];
    __syncthreads();
    #pragma unroll
    for (int k=0;k<16;++k){
      float dtv = dt_l[k][il];
      float a = expf(dtv*Av);
      Pv *= a;
      h = a*h + dtv*bm_l[k][s]*xi_l[k][il];
    }
    __syncthreads();
  }
  const int ci = b*DI + i;
  P[(ci*NCH + ch)*DS + s] = Pv;
  Q[(ci*NCH + ch)*DS + s] = h;
}

// ---------------- scan phase 2: sequential prefix over chunks (tiny)
__global__ __launch_bounds__(256) void k_scan2(const float* __restrict__ P, const float* __restrict__ Q,
                                               float* __restrict__ Hin){
  int tid = blockIdx.x*256 + threadIdx.x;   // B*DI*DS = 12288
  int s = tid & 15; int ci = tid >> 4;
  float h = 0.f;
  for (int ch=0; ch<NCH; ++ch){
    int idx = (ci*NCH+ch)*DS + s;
    Hin[idx] = h;
    h = P[idx]*h + Q[idx];
  }
}

// ---------------- scan phase 3: recompute with true init, emit y = (sum_s h*C + Dp*xi)*silu(z)
__global__ __launch_bounds__(256) void k_scan3(const float* __restrict__ dt,
    const float* __restrict__ xi, const float* __restrict__ Bm, const float* __restrict__ Cm,
    const float* __restrict__ zz, const u16* __restrict__ A_log, const u16* __restrict__ Dp,
    const float* __restrict__ Hin, float* __restrict__ Y){
  const int bid = blockIdx.x;
  const int ig = bid % (DI/16);
  const int ch = (bid/(DI/16)) % NCH;
  const int b  = bid/((DI/16)*NCH);
  const int tid = threadIdx.x;
  const int s = tid & 15, il = tid >> 4;
  const int i = ig*16 + il;
  const float Av = -expf(bf(A_log[i*DS + s]));
  const float Dv = bf(Dp[i]);
  __shared__ float dt_l[16][16], xi_l[16][16], bm_l[16][16], cm_l[16][16], z_l[16][16];
  const int ci = b*DI + i;
  float h = Hin[(ci*NCH + ch)*DS + s];
  const int n0 = ch*CL;
  for (int sub=0; sub<CL/16; ++sub){
    int n = n0 + sub*16 + il;
    dt_l[il][s] = dt[(b*NN + n)*DI + ig*16 + s];
    xi_l[il][s] = xi[(b*NN + n)*DI + ig*16 + s];
    z_l[il][s]  = zz[(b*NN + n)*DI + ig*16 + s];
    bm_l[il][s] = Bm[(b*NN + n)*DS + s];
    cm_l[il][s] = Cm[(b*NN + n)*DS + s];
    __syncthreads();
    #pragma unroll
    for (int k=0;k<16;++k){
      float dtv = dt_l[k][il];
      float a = expf(dtv*Av);
      h = a*h + dtv*bm_l[k][s]*xi_l[k][il];
      float c = h * cm_l[k][s];
      c += __shfl_xor(c,1); c += __shfl_xor(c,2); c += __shfl_xor(c,4); c += __shfl_xor(c,8);
      if (s==0){
        int n2 = n0 + sub*16 + k;
        float xiv = xi_l[k][il];
        float zv = z_l[k][il];
        float yv = (c + Dv*xiv) * (zv/(1.f+expf(-zv)));
        Y[(b*NN+n2)*DI + i] = yv;
      }
    }
    __syncthreads();
  }
}

// ---------------- out GEMM + residual: seq += Y @ out_w^T
__global__ __launch_bounds__(192) void k_out(const float* __restrict__ Y,
    const u16* __restrict__ out_w, float* __restrict__ seq){
  const int d = threadIdx.x;
  const int n0 = blockIdx.x*4;
  __shared__ float ys[4][DI];
  for (int k=d; k<4*DI; k+=192) ys[k/DI][k%DI] = Y[(n0 + k/DI)*DI + (k%DI)];
  __syncthreads();
  float a0=0.f,a1=0.f,a2=0.f,a3=0.f;
  const u16* w = out_w + d*DI;
  for (int c=0;c<DI;c+=8){
    u16x8 wv = *(const u16x8*)(w+c);
    float xv[4][8];
    #pragma unroll
    for (int t=0;t<4;++t){
      *(float4*)&xv[t][0] = *(const float4*)&ys[t][c];
      *(float4*)&xv[t][4] = *(const float4*)&ys[t][c+4];
    }
    #pragma unroll
    for (int j=0;j<8;++j){
      float wf = bf(wv[j]);
      a0 += wf*xv[0][j]; a1 += wf*xv[1][j]; a2 += wf*xv[2][j]; a3 += wf*xv[3][j];
    }
  }
  seq[(n0+0)*DD+d] += a0;
  seq[(n0+1)*DD+d] += a1;
  seq[(n0+2)*DD+d] += a2;
  seq[(n0+3)*DD+d] += a3;
}

// ---------------- final rmsnorm + transpose to (B,D,H,W); dtype per flag
__global__ __launch_bounds__(192) void k_final(const float* __restrict__ seq,
    const u16* __restrict__ normf_w, void* __restrict__ out, const int* __restrict__ flag){
  const int d = threadIdx.x;
  const int bn = blockIdx.x;
  const int b = bn >> 12, n = bn & (NN-1);
  __shared__ float wred[3];
  float v = seq[bn*DD + d];
  float s = v*v;
  #pragma unroll
  for (int off=32; off>=1; off>>=1) s += __shfl_down(s,off);
  if ((d&63)==0) wred[d>>6]=s;
  __syncthreads();
  float r = rsqrtf((wred[0]+wred[1]+wred[2])*(1.f/DD) + EPSF);
  float res = v * r * bf(normf_w[d]);
  int o = (b*DD+d)*NN + n;
  if (*flag) ((float*)out)[o] = res;
  else       ((u16*)out)[o]   = f2bf(res);
}

extern "C" void kernel_launch(void* const* d_in, const int* in_sizes, int n_in,
                              void* d_out, int out_size, void* d_ws, size_t ws_size,
                              hipStream_t stream){
  Ptrs ps;
  for (int i=0;i<16;++i) ps.p[i] = d_in[i];

  u16* arena = (u16*)d_ws;
  int* flag  = (int*)(arena + ARENA_TOTAL);
  float* fbase = (float*)((char*)d_ws + ARENA_BYTES);

  float* seq  = fbase;                 // NT*DD
  float* xn   = seq  + NT*DD;          // NT*DD (also hosts Pb/Qb after xn is dead)
  float* xi_r = xn   + NT*DD;          // NT*DI (reused as Y)
  float* zz   = xi_r + NT*DI;          // NT*DI
  float* xi   = zz   + NT*DI;          // NT*DI
  float* dt   = xi   + NT*DI;          // NT*DI
  float* Bm   = dt   + NT*DI;          // NT*DS
  float* Cm   = Bm   + NT*DS;          // NT*DS
  float* Hin  = Cm   + NT*DS;          // BB*DI*NCH*DS
  float* Pb   = xn;                    // BB*DI*NCH*DS (xn dead after k_inproj)
  float* Qb   = xn + BB*DI*NCH*DS;     // BB*DI*NCH*DS
  float* Y    = xi_r;

  const u16* xA      = arena + OFF_X;
  const u16* proj_w  = arena + OFF_PROJ_W;
  const u16* proj_b  = arena + OFF_PROJ_B;
  const u16* lp_w    = arena + OFF_LP_W;
  const u16* lp_b    = arena + OFF_LP_B;
  const u16* norm_w  = arena + OFF_NORM_W;
  const u16* in_w    = arena + OFF_IN_W;
  const u16* conv_w  = arena + OFF_CONV_W;
  const u16* conv_b  = arena + OFF_CONV_B;
  const u16* xproj_w = arena + OFF_XPROJ_W;
  const u16* dt_w    = arena + OFF_DT_W;
  const u16* dt_b    = arena + OFF_DT_B;
  const u16* A_log   = arena + OFF_A_LOG;
  const u16* Dp      = arena + OFF_DP;
  const u16* out_w   = arena + OFF_OUT_W;
  const u16* normf_w = arena + OFF_NORMF_W;

  k_detect<<<1, 256, 0, stream>>>((const u16*)d_in[0], flag);
  k_cvt<<<(ARENA_TOTAL+255)/256, 256, 0, stream>>>(ps, flag, arena);

  k_proj<<<(NT*DD+255)/256, 256, 0, stream>>>(xA, proj_w, proj_b, seq);
  for (int l=0; l<DEPTH; ++l){
    k_lp_norm<<<NT/4, 192, 0, stream>>>(seq, lp_w + l*DD*2*DD, lp_b + l*DD, norm_w + l*DD, xn);
    k_inproj<<<NT/4, 256, 0, stream>>>(xn, in_w + l*2*DI*DD, xi_r, zz);
    k_conv_proj<<<NT/8, 256, 0, stream>>>(xi_r, conv_w + l*DI*DC, conv_b + l*DI,
        xproj_w + l*(DTR+2*DS)*DI, dt_w + l*DI*DTR, dt_b + l*DI, xi, dt, Bm, Cm);
    k_scan1<<<BB*NCH*(DI/16), 256, 0, stream>>>(dt, xi, Bm, A_log + l*DI*DS, Pb, Qb);
    k_scan2<<<(BB*DI*DS)/256, 256, 0, stream>>>(Pb, Qb, Hin);
    k_scan3<<<BB*NCH*(DI/16), 256, 0, stream>>>(dt, xi, Bm, Cm, zz, A_log + l*DI*DS, Dp + l*DI, Hin, Y);
    k_out<<<NT/4, 192, 0, stream>>>(Y, out_w + l*DD*DI, seq);
  }
  k_final<<<NT, 192, 0, stream>>>(seq, normf_w, d_out, flag);
}

// Round 4
// 834.049 us; speedup vs baseline: 1.9166x; 1.9166x over previous
//
#include <hip/hip_runtime.h>
#include <hip/hip_bf16.h>

#define BB 2
#define NN 4096
#define DD 192
#define DI 384
#define DS 16
#define DTR 12
#define DC 4
#define DEPTH 4
#define NT (BB*NN)
#define NCH 64
#define CL 64
#define EPSF 1e-5f

// arena element offsets (u16 units)
#define OFF_X       0
#define OFF_PROJ_W  24576
#define OFF_PROJ_B  25152
#define OFF_LP_W    25344
#define OFF_LP_B    320256
#define OFF_NORM_W  321024
#define OFF_IN_W    321792
#define OFF_CONV_W  911616
#define OFF_CONV_B  917760
#define OFF_XPROJ_W 919296
#define OFF_DT_W    986880
#define OFF_DT_B    1005312
#define OFF_A_LOG   1006848
#define OFF_DP      1031424
#define OFF_OUT_W   1032960
#define OFF_NORMF_W 1327872
#define ARENA_TOTAL 1328064
#define ARENA_BYTES 2656160   // ARENA_TOTAL*2 + 32 pad (16B aligned)

typedef __hip_bfloat16 bf16_t;
typedef unsigned short u16;
typedef unsigned int u32;
typedef __attribute__((ext_vector_type(8))) unsigned short u16x8;
typedef __attribute__((ext_vector_type(8))) short s16x8;
typedef __attribute__((ext_vector_type(4))) float f32x4;

struct Ptrs { const void* p[16]; };

__device__ __forceinline__ float bf(u16 v){ return __uint_as_float(((u32)v)<<16); }
__device__ __forceinline__ u16 f2bf(float f){
  u32 b = __float_as_uint(f);
  return (u16)((b + 0x7FFFu + ((b>>16)&1u)) >> 16);
}

// ---------------- dtype detector: are inputs bf16(u16) or f32 storage?
__global__ __launch_bounds__(256) void k_detect(const u16* __restrict__ x, int* flag){
  __shared__ int cnt;
  if (threadIdx.x==0) cnt=0;
  __syncthreads();
  u32 v = x[2*threadIdx.x];
  int ex = (int)((v>>7)&0xFF);
  if (ex>=100 && ex<=140) atomicAdd(&cnt,1);
  __syncthreads();
  if (threadIdx.x==0) *flag = (cnt>128) ? 0 : 1;   // 0 = bf16 storage, 1 = f32 storage
}

// ---------------- canonicalize all inputs into bf16 arena
__global__ __launch_bounds__(256) void k_cvt(Ptrs ps, const int* __restrict__ flag, u16* __restrict__ arena){
  int e = blockIdx.x*256 + threadIdx.x;
  if (e >= ARENA_TOTAL) return;
  const void* sp; int off;
  if      (e < OFF_PROJ_W ){ sp=ps.p[0];  off=OFF_X; }
  else if (e < OFF_PROJ_B ){ sp=ps.p[1];  off=OFF_PROJ_W; }
  else if (e < OFF_LP_W   ){ sp=ps.p[2];  off=OFF_PROJ_B; }
  else if (e < OFF_LP_B   ){ sp=ps.p[3];  off=OFF_LP_W; }
  else if (e < OFF_NORM_W ){ sp=ps.p[4];  off=OFF_LP_B; }
  else if (e < OFF_IN_W   ){ sp=ps.p[5];  off=OFF_NORM_W; }
  else if (e < OFF_CONV_W ){ sp=ps.p[6];  off=OFF_IN_W; }
  else if (e < OFF_CONV_B ){ sp=ps.p[7];  off=OFF_CONV_W; }
  else if (e < OFF_XPROJ_W){ sp=ps.p[8];  off=OFF_CONV_B; }
  else if (e < OFF_DT_W   ){ sp=ps.p[9];  off=OFF_XPROJ_W; }
  else if (e < OFF_DT_B   ){ sp=ps.p[10]; off=OFF_DT_W; }
  else if (e < OFF_A_LOG  ){ sp=ps.p[11]; off=OFF_DT_B; }
  else if (e < OFF_DP     ){ sp=ps.p[12]; off=OFF_A_LOG; }
  else if (e < OFF_OUT_W  ){ sp=ps.p[13]; off=OFF_DP; }
  else if (e < OFF_NORMF_W){ sp=ps.p[14]; off=OFF_OUT_W; }
  else                     { sp=ps.p[15]; off=OFF_NORMF_W; }
  int k = e - off;
  if (*flag){
    u32 v = ((const u32*)sp)[k];
    arena[e] = (u16)((v + 0x7FFFu + ((v>>16)&1u)) >> 16);
  } else {
    arena[e] = ((const u16*)sp)[k];
  }
}

// ---------------- initial projection: seq[b,n,d] = sum_c x[b,c,n]*pw[d,c] + pb[d]
__global__ __launch_bounds__(256) void k_proj(const u16* __restrict__ x, const u16* __restrict__ pw,
                                              const u16* __restrict__ pb, float* __restrict__ seq){
  int idx = blockIdx.x*256 + threadIdx.x;
  if (idx >= NT*DD) return;
  int d = idx % DD; int bn = idx / DD; int b = bn >> 12; int n = bn & (NN-1);
  float acc = bf(pb[d]);
  acc += bf(x[(b*3+0)*NN + n]) * bf(pw[d*3+0]);
  acc += bf(x[(b*3+1)*NN + n]) * bf(pw[d*3+1]);
  acc += bf(x[(b*3+2)*NN + n]) * bf(pw[d*3+2]);
  seq[idx] = acc;
}

// ---------------- MFMA: shift+concat + lp GEMM + bias + rmsnorm -> xn (bf16)
// 32 tokens/block, N=192 full, K=384 streamed in chunks of 128.
__global__ __launch_bounds__(256) void k_lp_norm(const float* __restrict__ seq,
    const u16* __restrict__ lp_w, const u16* __restrict__ lp_b, const u16* __restrict__ norm_w,
    u16* __restrict__ xn){
  const int tid = threadIdx.x;
  const int n0 = blockIdx.x*32;
  __shared__ u16 combL[32][392];     // 384 + 8 pad
  __shared__ u16 wL[192][136];       // 128 + 8 pad
  __shared__ float accL[32][200];    // 192 + 8 pad
  __shared__ float ssq[32];

  // stage comb (bf16): [t][0:192]=cur, [t][192:384]=cur-prev
  for (int idx = tid*4; idx < 32*DD; idx += 1024){
    int t = idx/DD, d = idx%DD;
    int gn = n0 + t;
    float4 cur = *(const float4*)&seq[gn*DD + d];
    float4 prv = make_float4(0.f,0.f,0.f,0.f);
    if ((gn & (NN-1)) != 0) prv = *(const float4*)&seq[(gn-1)*DD + d];
    combL[t][d+0]=f2bf(cur.x); combL[t][d+1]=f2bf(cur.y); combL[t][d+2]=f2bf(cur.z); combL[t][d+3]=f2bf(cur.w);
    combL[t][DD+d+0]=f2bf(cur.x-prv.x); combL[t][DD+d+1]=f2bf(cur.y-prv.y);
    combL[t][DD+d+2]=f2bf(cur.z-prv.z); combL[t][DD+d+3]=f2bf(cur.w-prv.w);
  }

  const int w = tid >> 6;          // wave 0..3
  const int lane = tid & 63;
  const int lm = lane & 15, lk = lane >> 4;
  const int mt = w & 1;            // m-subtile 0..1
  const int nbase = (w >> 1)*6;    // n-subtiles [nbase, nbase+6)

  f32x4 acc[6];
  #pragma unroll
  for (int i=0;i<6;++i) acc[i] = (f32x4){0.f,0.f,0.f,0.f};

  for (int c=0;c<3;++c){
    const int kc = c*128;
    // stage lp_w chunk [192][128]
    for (int idx = tid*8; idx < 192*128; idx += 2048){
      int row = idx >> 7, col = idx & 127;
      *(u16x8*)&wL[row][col] = *(const u16x8*)(lp_w + row*384 + kc + col);
    }
    __syncthreads();
    #pragma unroll
    for (int ks=0; ks<4; ++ks){
      s16x8 a = *(s16x8*)&combL[mt*16 + lm][kc + ks*32 + lk*8];
      #pragma unroll
      for (int nt=0; nt<6; ++nt){
        s16x8 b = *(s16x8*)&wL[(nbase+nt)*16 + lm][ks*32 + lk*8];
        acc[nt] = __builtin_amdgcn_mfma_f32_16x16x32_bf16(a, b, acc[nt], 0, 0, 0);
      }
    }
    __syncthreads();
  }
  // spill acc + bias to LDS
  #pragma unroll
  for (int nt=0; nt<6; ++nt){
    #pragma unroll
    for (int r=0; r<4; ++r){
      int m = mt*16 + lk*4 + r;
      int n = (nbase+nt)*16 + lm;
      accL[m][n] = acc[nt][r] + bf(lp_b[n]);
    }
  }
  __syncthreads();
  // rmsnorm: 8 threads per token
  {
    int tok = tid >> 3, j = tid & 7;
    float s = 0.f;
    #pragma unroll
    for (int c=0;c<24;++c){ float v = accL[tok][j*24+c]; s += v*v; }
    s += __shfl_xor(s,1); s += __shfl_xor(s,2); s += __shfl_xor(s,4);
    if (j==0) ssq[tok] = rsqrtf(s*(1.f/DD) + EPSF);
  }
  __syncthreads();
  for (int idx = tid; idx < 32*DD; idx += 256){
    int t = idx/DD, d = idx%DD;
    xn[(n0+t)*DD + d] = f2bf(accL[t][d] * ssq[t] * bf(norm_w[d]));
  }
}

// ---------------- MFMA in_w GEMM: [8192x768] = xn[8192x192] x in_w[768x192]^T
// 64x64 tiles; writes xi_c / zz_b (bf16)
__global__ __launch_bounds__(256) void k_inproj(const u16* __restrict__ xn,
    const u16* __restrict__ in_w, u16* __restrict__ xi_c, u16* __restrict__ zz_b){
  const int tid = threadIdx.x;
  const int m0 = blockIdx.x*64;
  const int e0 = blockIdx.y*64;
  __shared__ u16 aL[64][200];
  __shared__ u16 bL[64][200];
  for (int idx = tid*8; idx < 64*192; idx += 2048){
    int row = idx/192, col = idx%192;
    *(u16x8*)&aL[row][col] = *(const u16x8*)(xn   + (m0+row)*192 + col);
    *(u16x8*)&bL[row][col] = *(const u16x8*)(in_w + (e0+row)*192 + col);
  }
  __syncthreads();
  const int w = tid >> 6, lane = tid & 63;
  const int lm = lane & 15, lk = lane >> 4;
  f32x4 acc[4];
  #pragma unroll
  for (int i=0;i<4;++i) acc[i] = (f32x4){0.f,0.f,0.f,0.f};
  #pragma unroll
  for (int ks=0; ks<6; ++ks){
    s16x8 a = *(s16x8*)&aL[w*16 + lm][ks*32 + lk*8];
    #pragma unroll
    for (int nt=0; nt<4; ++nt){
      s16x8 b = *(s16x8*)&bL[nt*16 + lm][ks*32 + lk*8];
      acc[nt] = __builtin_amdgcn_mfma_f32_16x16x32_bf16(a, b, acc[nt], 0, 0, 0);
    }
  }
  #pragma unroll
  for (int nt=0; nt<4; ++nt){
    int e = e0 + nt*16 + lm;
    #pragma unroll
    for (int r=0; r<4; ++r){
      int tok = m0 + w*16 + lk*4 + r;
      u16 v = f2bf(acc[nt][r]);
      if (e0 < DI) xi_c[tok*DI + e]      = v;
      else         zz_b[tok*DI + e - DI] = v;
    }
  }
}

// ---------------- causal conv(k=4) + silu + xproj(44) + dt softplus (xi_c bf16 in)
__global__ __launch_bounds__(256) void k_conv_proj(const u16* __restrict__ xi_c,
    const u16* __restrict__ conv_w, const u16* __restrict__ conv_b,
    const u16* __restrict__ xproj_w, const u16* __restrict__ dt_w, const u16* __restrict__ dt_b,
    float* __restrict__ xi, float* __restrict__ dt_o, float* __restrict__ Bm, float* __restrict__ Cm){
  const int tid = threadIdx.x;
  const int n0 = blockIdx.x*8;
  const int b = n0 >> 12;
  __shared__ float xr[11][DI];
  __shared__ float xs[8][DI];
  __shared__ float dbc_s[8][44];
  for (int k=tid;k<11*DI;k+=256){
    int r=k/DI, i=k-r*DI;
    int bn=n0-3+r;
    float v=0.f;
    if (bn>=0 && (bn>>12)==b) v = bf(xi_c[bn*DI+i]);
    xr[r][i]=v;
  }
  __syncthreads();
  for (int k=tid;k<8*DI;k+=256){
    int t=k/DI, i=k-t*DI;
    float acc = bf(conv_b[i]);
    #pragma unroll
    for (int q=0;q<4;++q) acc += xr[t+q][i]*bf(conv_w[i*4+q]);
    float v = acc/(1.f+expf(-acc));
    xs[t][i]=v;
    xi[(n0+t)*DI+i]=v;
  }
  __syncthreads();
  for (int k=tid;k<8*44;k+=256){
    int t=k/44, e=k-t*44;
    const u16* w = xproj_w + e*DI;
    float acc=0.f;
    for (int c=0;c<DI;c+=8){
      u16x8 wv=*(const u16x8*)(w+c);
      float xv[8];
      *(float4*)&xv[0] = *(const float4*)&xs[t][c];
      *(float4*)&xv[4] = *(const float4*)&xs[t][c+4];
      #pragma unroll
      for (int j=0;j<8;++j) acc += bf(wv[j])*xv[j];
    }
    dbc_s[t][e]=acc;
    int bn=n0+t;
    if (e>=DTR && e<DTR+DS) Bm[bn*DS + e-DTR]=acc;
    else if (e>=DTR+DS) Cm[bn*DS + e-DTR-DS]=acc;
  }
  __syncthreads();
  for (int k=tid;k<8*DI;k+=256){
    int t=k/DI, i=k-t*DI;
    float acc = bf(dt_b[i]);
    #pragma unroll
    for (int j=0;j<DTR;++j) acc += dbc_s[t][j]*bf(dt_w[i*DTR+j]);
    float sp = (acc>20.f)? acc : log1pf(expf(acc));
    dt_o[(n0+t)*DI+i]=sp;
  }
}

// ---------------- scan phase 1: per-chunk local scan -> P, Q
__global__ __launch_bounds__(256) void k_scan1(const float* __restrict__ dt,
    const float* __restrict__ xi, const float* __restrict__ Bm,
    const u16* __restrict__ A_log, float* __restrict__ P, float* __restrict__ Q){
  const int bid = blockIdx.x;
  const int ig = bid % (DI/16);
  const int ch = (bid/(DI/16)) % NCH;
  const int b  = bid/((DI/16)*NCH);
  const int tid = threadIdx.x;
  const int s = tid & 15, il = tid >> 4;
  const int i = ig*16 + il;
  const float Av = -expf(bf(A_log[i*DS + s]));
  __shared__ float dt_l[16][16], xi_l[16][16], bm_l[16][16];
  float Pv = 1.f, h = 0.f;
  const int n0 = ch*CL;
  for (int sub=0; sub<CL/16; ++sub){
    int n = n0 + sub*16 + il;
    dt_l[il][s] = dt[(b*NN + n)*DI + ig*16 + s];
    xi_l[il][s] = xi[(b*NN + n)*DI + ig*16 + s];
    bm_l[il][s] = Bm[(b*NN + n)*DS + s];
    __syncthreads();
    #pragma unroll
    for (int k=0;k<16;++k){
      float dtv = dt_l[k][il];
      float a = expf(dtv*Av);
      Pv *= a;
      h = a*h + dtv*bm_l[k][s]*xi_l[k][il];
    }
    __syncthreads();
  }
  const int ci = b*DI + i;
  P[(ci*NCH + ch)*DS + s] = Pv;
  Q[(ci*NCH + ch)*DS + s] = h;
}

// ---------------- scan phase 2: sequential prefix over chunks (tiny)
__global__ __launch_bounds__(256) void k_scan2(const float* __restrict__ P, const float* __restrict__ Q,
                                               float* __restrict__ Hin){
  int tid = blockIdx.x*256 + threadIdx.x;   // B*DI*DS = 12288
  int s = tid & 15; int ci = tid >> 4;
  float h = 0.f;
  for (int ch=0; ch<NCH; ++ch){
    int idx = (ci*NCH+ch)*DS + s;
    Hin[idx] = h;
    h = P[idx]*h + Q[idx];
  }
}

// ---------------- scan phase 3: recompute with true init, emit y bf16
__global__ __launch_bounds__(256) void k_scan3(const float* __restrict__ dt,
    const float* __restrict__ xi, const float* __restrict__ Bm, const float* __restrict__ Cm,
    const u16* __restrict__ zz_b, const u16* __restrict__ A_log, const u16* __restrict__ Dp,
    const float* __restrict__ Hin, u16* __restrict__ Y){
  const int bid = blockIdx.x;
  const int ig = bid % (DI/16);
  const int ch = (bid/(DI/16)) % NCH;
  const int b  = bid/((DI/16)*NCH);
  const int tid = threadIdx.x;
  const int s = tid & 15, il = tid >> 4;
  const int i = ig*16 + il;
  const float Av = -expf(bf(A_log[i*DS + s]));
  const float Dv = bf(Dp[i]);
  __shared__ float dt_l[16][16], xi_l[16][16], bm_l[16][16], cm_l[16][16], z_l[16][16];
  const int ci = b*DI + i;
  float h = Hin[(ci*NCH + ch)*DS + s];
  const int n0 = ch*CL;
  for (int sub=0; sub<CL/16; ++sub){
    int n = n0 + sub*16 + il;
    dt_l[il][s] = dt[(b*NN + n)*DI + ig*16 + s];
    xi_l[il][s] = xi[(b*NN + n)*DI + ig*16 + s];
    z_l[il][s]  = bf(zz_b[(b*NN + n)*DI + ig*16 + s]);
    bm_l[il][s] = Bm[(b*NN + n)*DS + s];
    cm_l[il][s] = Cm[(b*NN + n)*DS + s];
    __syncthreads();
    #pragma unroll
    for (int k=0;k<16;++k){
      float dtv = dt_l[k][il];
      float a = expf(dtv*Av);
      h = a*h + dtv*bm_l[k][s]*xi_l[k][il];
      float c = h * cm_l[k][s];
      c += __shfl_xor(c,1); c += __shfl_xor(c,2); c += __shfl_xor(c,4); c += __shfl_xor(c,8);
      if (s==0){
        int n2 = n0 + sub*16 + k;
        float xiv = xi_l[k][il];
        float zv = z_l[k][il];
        float yv = (c + Dv*xiv) * (zv/(1.f+expf(-zv)));
        Y[(b*NN+n2)*DI + i] = f2bf(yv);
      }
    }
    __syncthreads();
  }
}

// ---------------- MFMA out GEMM + residual: seq += Y[8192x384] x out_w[192x384]^T
__global__ __launch_bounds__(256) void k_out(const u16* __restrict__ Y,
    const u16* __restrict__ out_w, float* __restrict__ seq){
  const int tid = threadIdx.x;
  const int m0 = blockIdx.x*64;
  const int d0 = blockIdx.y*64;
  __shared__ u16 aL[64][200];
  __shared__ u16 bL[64][200];
  const int w = tid >> 6, lane = tid & 63;
  const int lm = lane & 15, lk = lane >> 4;
  f32x4 acc[4];
  #pragma unroll
  for (int i=0;i<4;++i) acc[i] = (f32x4){0.f,0.f,0.f,0.f};
  for (int c=0; c<2; ++c){
    const int kc = c*192;
    for (int idx = tid*8; idx < 64*192; idx += 2048){
      int row = idx/192, col = idx%192;
      *(u16x8*)&aL[row][col] = *(const u16x8*)(Y     + (m0+row)*DI + kc + col);
      *(u16x8*)&bL[row][col] = *(const u16x8*)(out_w + (d0+row)*DI + kc + col);
    }
    __syncthreads();
    #pragma unroll
    for (int ks=0; ks<6; ++ks){
      s16x8 a = *(s16x8*)&aL[w*16 + lm][ks*32 + lk*8];
      #pragma unroll
      for (int nt=0; nt<4; ++nt){
        s16x8 b = *(s16x8*)&bL[nt*16 + lm][ks*32 + lk*8];
        acc[nt] = __builtin_amdgcn_mfma_f32_16x16x32_bf16(a, b, acc[nt], 0, 0, 0);
      }
    }
    __syncthreads();
  }
  #pragma unroll
  for (int nt=0; nt<4; ++nt){
    int d = d0 + nt*16 + lm;
    #pragma unroll
    for (int r=0; r<4; ++r){
      int tok = m0 + w*16 + lk*4 + r;
      seq[tok*DD + d] += acc[nt][r];
    }
  }
}

// ---------------- final rmsnorm + transpose to (B,D,H,W); dtype per flag
__global__ __launch_bounds__(192) void k_final(const float* __restrict__ seq,
    const u16* __restrict__ normf_w, void* __restrict__ out, const int* __restrict__ flag){
  const int d = threadIdx.x;
  const int bn = blockIdx.x;
  const int b = bn >> 12, n = bn & (NN-1);
  __shared__ float wred[3];
  float v = seq[bn*DD + d];
  float s = v*v;
  #pragma unroll
  for (int off=32; off>=1; off>>=1) s += __shfl_down(s,off);
  if ((d&63)==0) wred[d>>6]=s;
  __syncthreads();
  float r = rsqrtf((wred[0]+wred[1]+wred[2])*(1.f/DD) + EPSF);
  float res = v * r * bf(normf_w[d]);
  int o = (b*DD+d)*NN + n;
  if (*flag) ((float*)out)[o] = res;
  else       ((u16*)out)[o]   = f2bf(res);
}

extern "C" void kernel_launch(void* const* d_in, const int* in_sizes, int n_in,
                              void* d_out, int out_size, void* d_ws, size_t ws_size,
                              hipStream_t stream){
  Ptrs ps;
  for (int i=0;i<16;++i) ps.p[i] = d_in[i];

  u16* arena = (u16*)d_ws;
  int* flag  = (int*)(arena + ARENA_TOTAL);
  float* fbase = (float*)((char*)d_ws + ARENA_BYTES);

  float* seq  = fbase;                 // 1,572,864
  float* xi   = seq  + NT*DD;          // 3,145,728
  float* dt   = xi   + NT*DI;          // 3,145,728
  float* Bm   = dt   + NT*DI;          // 131,072
  float* Cm   = Bm   + NT*DS;          // 131,072
  float* Hin  = Cm   + NT*DS;          // 786,432
  float* Pb   = Hin  + BB*DI*NCH*DS;   // 786,432
  float* Qb   = Pb   + BB*DI*NCH*DS;   // 786,432
  u16* xn_b   = (u16*)(Qb + BB*DI*NCH*DS);
  u16* xi_c   = xn_b + NT*DD;
  u16* zz_b   = xi_c + NT*DI;
  u16* Y_b    = zz_b + NT*DI;

  const u16* xA      = arena + OFF_X;
  const u16* proj_w  = arena + OFF_PROJ_W;
  const u16* proj_b  = arena + OFF_PROJ_B;
  const u16* lp_w    = arena + OFF_LP_W;
  const u16* lp_b    = arena + OFF_LP_B;
  const u16* norm_w  = arena + OFF_NORM_W;
  const u16* in_w    = arena + OFF_IN_W;
  const u16* conv_w  = arena + OFF_CONV_W;
  const u16* conv_b  = arena + OFF_CONV_B;
  const u16* xproj_w = arena + OFF_XPROJ_W;
  const u16* dt_w    = arena + OFF_DT_W;
  const u16* dt_b    = arena + OFF_DT_B;
  const u16* A_log   = arena + OFF_A_LOG;
  const u16* Dp      = arena + OFF_DP;
  const u16* out_w   = arena + OFF_OUT_W;
  const u16* normf_w = arena + OFF_NORMF_W;

  k_detect<<<1, 256, 0, stream>>>((const u16*)d_in[0], flag);
  k_cvt<<<(ARENA_TOTAL+255)/256, 256, 0, stream>>>(ps, flag, arena);

  k_proj<<<(NT*DD+255)/256, 256, 0, stream>>>(xA, proj_w, proj_b, seq);
  for (int l=0; l<DEPTH; ++l){
    k_lp_norm<<<NT/32, 256, 0, stream>>>(seq, lp_w + l*DD*2*DD, lp_b + l*DD, norm_w + l*DD, xn_b);
    k_inproj<<<dim3(NT/64, 12), 256, 0, stream>>>(xn_b, in_w + l*2*DI*DD, xi_c, zz_b);
    k_conv_proj<<<NT/8, 256, 0, stream>>>(xi_c, conv_w + l*DI*DC, conv_b + l*DI,
        xproj_w + l*(DTR+2*DS)*DI, dt_w + l*DI*DTR, dt_b + l*DI, xi, dt, Bm, Cm);
    k_scan1<<<BB*NCH*(DI/16), 256, 0, stream>>>(dt, xi, Bm, A_log + l*DI*DS, Pb, Qb);
    k_scan2<<<(BB*DI*DS)/256, 256, 0, stream>>>(Pb, Qb, Hin);
    k_scan3<<<BB*NCH*(DI/16), 256, 0, stream>>>(dt, xi, Bm, Cm, zz_b, A_log + l*DI*DS, Dp + l*DI, Hin, Y_b);
    k_out<<<dim3(NT/64, 3), 256, 0, stream>>>(Y_b, out_w + l*DD*DI, seq);
  }
  k_final<<<NT, 192, 0, stream>>>(seq, normf_w, d_out, flag);
}

// Round 5
// 697.396 us; speedup vs baseline: 2.2922x; 1.1959x over previous
//
#include <hip/hip_runtime.h>
#include <hip/hip_bf16.h>

#define BB 2
#define NN 4096
#define DD 192
#define DI 384
#define DS 16
#define DTR 12
#define DC 4
#define DEPTH 4
#define NT (BB*NN)
#define NCH 128
#define CL 32
#define EPSF 1e-5f

// arena element offsets (u16 units)
#define OFF_X       0
#define OFF_PROJ_W  24576
#define OFF_PROJ_B  25152
#define OFF_LP_W    25344
#define OFF_LP_B    320256
#define OFF_NORM_W  321024
#define OFF_IN_W    321792
#define OFF_CONV_W  911616
#define OFF_CONV_B  917760
#define OFF_XPROJ_W 919296
#define OFF_DT_W    986880
#define OFF_DT_B    1005312
#define OFF_A_LOG   1006848
#define OFF_DP      1031424
#define OFF_OUT_W   1032960
#define OFF_NORMF_W 1327872
#define ARENA_TOTAL 1328064
#define ARENA_BYTES 2656160   // ARENA_TOTAL*2 + 32 pad (16B aligned)

typedef __hip_bfloat16 bf16_t;
typedef unsigned short u16;
typedef unsigned int u32;
typedef __attribute__((ext_vector_type(8))) unsigned short u16x8;
typedef __attribute__((ext_vector_type(8))) short s16x8;
typedef __attribute__((ext_vector_type(4))) float f32x4;

struct Ptrs { const void* p[16]; };

__device__ __forceinline__ float bf(u16 v){ return __uint_as_float(((u32)v)<<16); }
__device__ __forceinline__ u16 f2bf(float f){
  u32 b = __float_as_uint(f);
  return (u16)((b + 0x7FFFu + ((b>>16)&1u)) >> 16);
}

// ---------------- dtype detector: are inputs bf16(u16) or f32 storage?
__global__ __launch_bounds__(256) void k_detect(const u16* __restrict__ x, int* flag){
  __shared__ int cnt;
  if (threadIdx.x==0) cnt=0;
  __syncthreads();
  u32 v = x[2*threadIdx.x];
  int ex = (int)((v>>7)&0xFF);
  if (ex>=100 && ex<=140) atomicAdd(&cnt,1);
  __syncthreads();
  if (threadIdx.x==0) *flag = (cnt>128) ? 0 : 1;   // 0 = bf16 storage, 1 = f32 storage
}

// ---------------- canonicalize all inputs into bf16 arena
__global__ __launch_bounds__(256) void k_cvt(Ptrs ps, const int* __restrict__ flag, u16* __restrict__ arena){
  int e = blockIdx.x*256 + threadIdx.x;
  if (e >= ARENA_TOTAL) return;
  const void* sp; int off;
  if      (e < OFF_PROJ_W ){ sp=ps.p[0];  off=OFF_X; }
  else if (e < OFF_PROJ_B ){ sp=ps.p[1];  off=OFF_PROJ_W; }
  else if (e < OFF_LP_W   ){ sp=ps.p[2];  off=OFF_PROJ_B; }
  else if (e < OFF_LP_B   ){ sp=ps.p[3];  off=OFF_LP_W; }
  else if (e < OFF_NORM_W ){ sp=ps.p[4];  off=OFF_LP_B; }
  else if (e < OFF_IN_W   ){ sp=ps.p[5];  off=OFF_NORM_W; }
  else if (e < OFF_CONV_W ){ sp=ps.p[6];  off=OFF_IN_W; }
  else if (e < OFF_CONV_B ){ sp=ps.p[7];  off=OFF_CONV_W; }
  else if (e < OFF_XPROJ_W){ sp=ps.p[8];  off=OFF_CONV_B; }
  else if (e < OFF_DT_W   ){ sp=ps.p[9];  off=OFF_XPROJ_W; }
  else if (e < OFF_DT_B   ){ sp=ps.p[10]; off=OFF_DT_W; }
  else if (e < OFF_A_LOG  ){ sp=ps.p[11]; off=OFF_DT_B; }
  else if (e < OFF_DP     ){ sp=ps.p[12]; off=OFF_A_LOG; }
  else if (e < OFF_OUT_W  ){ sp=ps.p[13]; off=OFF_DP; }
  else if (e < OFF_NORMF_W){ sp=ps.p[14]; off=OFF_OUT_W; }
  else                     { sp=ps.p[15]; off=OFF_NORMF_W; }
  int k = e - off;
  if (*flag){
    u32 v = ((const u32*)sp)[k];
    arena[e] = (u16)((v + 0x7FFFu + ((v>>16)&1u)) >> 16);
  } else {
    arena[e] = ((const u16*)sp)[k];
  }
}

// ---------------- initial projection: seq[b,n,d] = sum_c x[b,c,n]*pw[d,c] + pb[d]
__global__ __launch_bounds__(256) void k_proj(const u16* __restrict__ x, const u16* __restrict__ pw,
                                              const u16* __restrict__ pb, float* __restrict__ seq){
  int idx = blockIdx.x*256 + threadIdx.x;
  if (idx >= NT*DD) return;
  int d = idx % DD; int bn = idx / DD; int b = bn >> 12; int n = bn & (NN-1);
  float acc = bf(pb[d]);
  acc += bf(x[(b*3+0)*NN + n]) * bf(pw[d*3+0]);
  acc += bf(x[(b*3+1)*NN + n]) * bf(pw[d*3+1]);
  acc += bf(x[(b*3+2)*NN + n]) * bf(pw[d*3+2]);
  seq[idx] = acc;
}

// ---------------- MFMA: shift+concat + lp GEMM + bias + rmsnorm -> xn (bf16)
__global__ __launch_bounds__(256) void k_lp_norm(const float* __restrict__ seq,
    const u16* __restrict__ lp_w, const u16* __restrict__ lp_b, const u16* __restrict__ norm_w,
    u16* __restrict__ xn){
  const int tid = threadIdx.x;
  const int n0 = blockIdx.x*32;
  __shared__ u16 combL[32][392];     // 384 + 8 pad
  __shared__ u16 wL[192][136];       // 128 + 8 pad
  __shared__ float accL[32][200];    // 192 + 8 pad
  __shared__ float ssq[32];

  for (int idx = tid*4; idx < 32*DD; idx += 1024){
    int t = idx/DD, d = idx%DD;
    int gn = n0 + t;
    float4 cur = *(const float4*)&seq[gn*DD + d];
    float4 prv = make_float4(0.f,0.f,0.f,0.f);
    if ((gn & (NN-1)) != 0) prv = *(const float4*)&seq[(gn-1)*DD + d];
    combL[t][d+0]=f2bf(cur.x); combL[t][d+1]=f2bf(cur.y); combL[t][d+2]=f2bf(cur.z); combL[t][d+3]=f2bf(cur.w);
    combL[t][DD+d+0]=f2bf(cur.x-prv.x); combL[t][DD+d+1]=f2bf(cur.y-prv.y);
    combL[t][DD+d+2]=f2bf(cur.z-prv.z); combL[t][DD+d+3]=f2bf(cur.w-prv.w);
  }

  const int w = tid >> 6;
  const int lane = tid & 63;
  const int lm = lane & 15, lk = lane >> 4;
  const int mt = w & 1;
  const int nbase = (w >> 1)*6;

  f32x4 acc[6];
  #pragma unroll
  for (int i=0;i<6;++i) acc[i] = (f32x4){0.f,0.f,0.f,0.f};

  for (int c=0;c<3;++c){
    const int kc = c*128;
    for (int idx = tid*8; idx < 192*128; idx += 2048){
      int row = idx >> 7, col = idx & 127;
      *(u16x8*)&wL[row][col] = *(const u16x8*)(lp_w + row*384 + kc + col);
    }
    __syncthreads();
    #pragma unroll
    for (int ks=0; ks<4; ++ks){
      s16x8 a = *(s16x8*)&combL[mt*16 + lm][kc + ks*32 + lk*8];
      #pragma unroll
      for (int nt=0; nt<6; ++nt){
        s16x8 b = *(s16x8*)&wL[(nbase+nt)*16 + lm][ks*32 + lk*8];
        acc[nt] = __builtin_amdgcn_mfma_f32_16x16x32_bf16(a, b, acc[nt], 0, 0, 0);
      }
    }
    __syncthreads();
  }
  #pragma unroll
  for (int nt=0; nt<6; ++nt){
    #pragma unroll
    for (int r=0; r<4; ++r){
      int m = mt*16 + lk*4 + r;
      int n = (nbase+nt)*16 + lm;
      accL[m][n] = acc[nt][r] + bf(lp_b[n]);
    }
  }
  __syncthreads();
  {
    int tok = tid >> 3, j = tid & 7;
    float s = 0.f;
    #pragma unroll
    for (int c=0;c<24;++c){ float v = accL[tok][j*24+c]; s += v*v; }
    s += __shfl_xor(s,1); s += __shfl_xor(s,2); s += __shfl_xor(s,4);
    if (j==0) ssq[tok] = rsqrtf(s*(1.f/DD) + EPSF);
  }
  __syncthreads();
  for (int idx = tid; idx < 32*DD; idx += 256){
    int t = idx/DD, d = idx%DD;
    xn[(n0+t)*DD + d] = f2bf(accL[t][d] * ssq[t] * bf(norm_w[d]));
  }
}

// ---------------- MFMA in_w GEMM: [8192x768] = xn[8192x192] x in_w[768x192]^T
__global__ __launch_bounds__(256) void k_inproj(const u16* __restrict__ xn,
    const u16* __restrict__ in_w, u16* __restrict__ xi_c, u16* __restrict__ zz_b){
  const int tid = threadIdx.x;
  const int m0 = blockIdx.x*64;
  const int e0 = blockIdx.y*64;
  __shared__ u16 aL[64][200];
  __shared__ u16 bL[64][200];
  for (int idx = tid*8; idx < 64*192; idx += 2048){
    int row = idx/192, col = idx%192;
    *(u16x8*)&aL[row][col] = *(const u16x8*)(xn   + (m0+row)*192 + col);
    *(u16x8*)&bL[row][col] = *(const u16x8*)(in_w + (e0+row)*192 + col);
  }
  __syncthreads();
  const int w = tid >> 6, lane = tid & 63;
  const int lm = lane & 15, lk = lane >> 4;
  f32x4 acc[4];
  #pragma unroll
  for (int i=0;i<4;++i) acc[i] = (f32x4){0.f,0.f,0.f,0.f};
  #pragma unroll
  for (int ks=0; ks<6; ++ks){
    s16x8 a = *(s16x8*)&aL[w*16 + lm][ks*32 + lk*8];
    #pragma unroll
    for (int nt=0; nt<4; ++nt){
      s16x8 b = *(s16x8*)&bL[nt*16 + lm][ks*32 + lk*8];
      acc[nt] = __builtin_amdgcn_mfma_f32_16x16x32_bf16(a, b, acc[nt], 0, 0, 0);
    }
  }
  #pragma unroll
  for (int nt=0; nt<4; ++nt){
    int e = e0 + nt*16 + lm;
    #pragma unroll
    for (int r=0; r<4; ++r){
      int tok = m0 + w*16 + lk*4 + r;
      u16 v = f2bf(acc[nt][r]);
      if (e0 < DI) xi_c[tok*DI + e]      = v;
      else         zz_b[tok*DI + e - DI] = v;
    }
  }
}

// ---------------- causal conv(k=4) + silu + xproj(44) + dt softplus (xi_c bf16 in)
__global__ __launch_bounds__(256) void k_conv_proj(const u16* __restrict__ xi_c,
    const u16* __restrict__ conv_w, const u16* __restrict__ conv_b,
    const u16* __restrict__ xproj_w, const u16* __restrict__ dt_w, const u16* __restrict__ dt_b,
    float* __restrict__ xi, float* __restrict__ dt_o, float* __restrict__ Bm, float* __restrict__ Cm){
  const int tid = threadIdx.x;
  const int n0 = blockIdx.x*8;
  const int b = n0 >> 12;
  __shared__ float xr[11][DI];
  __shared__ float xs[8][DI];
  __shared__ float dbc_s[8][44];
  for (int k=tid;k<11*DI;k+=256){
    int r=k/DI, i=k-r*DI;
    int bn=n0-3+r;
    float v=0.f;
    if (bn>=0 && (bn>>12)==b) v = bf(xi_c[bn*DI+i]);
    xr[r][i]=v;
  }
  __syncthreads();
  for (int k=tid;k<8*DI;k+=256){
    int t=k/DI, i=k-t*DI;
    float acc = bf(conv_b[i]);
    #pragma unroll
    for (int q=0;q<4;++q) acc += xr[t+q][i]*bf(conv_w[i*4+q]);
    float v = acc/(1.f+__expf(-acc));
    xs[t][i]=v;
    xi[(n0+t)*DI+i]=v;
  }
  __syncthreads();
  for (int k=tid;k<8*44;k+=256){
    int t=k/44, e=k-t*44;
    const u16* w = xproj_w + e*DI;
    float acc=0.f;
    for (int c=0;c<DI;c+=8){
      u16x8 wv=*(const u16x8*)(w+c);
      float xv[8];
      *(float4*)&xv[0] = *(const float4*)&xs[t][c];
      *(float4*)&xv[4] = *(const float4*)&xs[t][c+4];
      #pragma unroll
      for (int j=0;j<8;++j) acc += bf(wv[j])*xv[j];
    }
    dbc_s[t][e]=acc;
    int bn=n0+t;
    if (e>=DTR && e<DTR+DS) Bm[bn*DS + e-DTR]=acc;
    else if (e>=DTR+DS) Cm[bn*DS + e-DTR-DS]=acc;
  }
  __syncthreads();
  for (int k=tid;k<8*DI;k+=256){
    int t=k/DI, i=k-t*DI;
    float acc = bf(dt_b[i]);
    #pragma unroll
    for (int j=0;j<DTR;++j) acc += dbc_s[t][j]*bf(dt_w[i*DTR+j]);
    float sp = (acc>20.f)? acc : log1pf(expf(acc));
    dt_o[(n0+t)*DI+i]=sp;
  }
}

// ---------------- scan phase 1: per-chunk local scan, states in registers -> P, Q
__global__ __launch_bounds__(128) void k_scan1(const float* __restrict__ dt,
    const float* __restrict__ xi, const float* __restrict__ Bm,
    const u16* __restrict__ A_log, float* __restrict__ P, float* __restrict__ Q){
  const int tid = threadIdx.x;
  const int i = blockIdx.x*128 + tid;
  const int ch = blockIdx.y, b = blockIdx.z;
  __shared__ float bm_l[CL][DS];
  {
    int r = tid>>2, c4 = (tid&3)*4;
    *(float4*)&bm_l[r][c4] = *(const float4*)&Bm[(b*NN + ch*CL + r)*DS + c4];
  }
  float Av[DS];
  {
    u16x8 a0 = *(const u16x8*)(A_log + i*DS);
    u16x8 a1 = *(const u16x8*)(A_log + i*DS + 8);
    #pragma unroll
    for (int s=0;s<8;++s){ Av[s] = -__expf(bf(a0[s])*0.6931471805599453f*1.4426950408889634f); }
    #pragma unroll
    for (int s=0;s<8;++s){ Av[8+s] = -__expf(bf(a1[s])); }
    #pragma unroll
    for (int s=0;s<8;++s){ Av[s] = -__expf(bf(a0[s])); }
  }
  __syncthreads();
  float Pv[DS], h[DS];
  #pragma unroll
  for (int s=0;s<DS;++s){ Pv[s]=1.f; h[s]=0.f; }
  const int nb = b*NN + ch*CL;
  #pragma unroll 4
  for (int t=0;t<CL;++t){
    float dtv = dt[(nb+t)*DI + i];
    float xv  = xi[(nb+t)*DI + i];
    float dtx = dtv*xv;
    #pragma unroll
    for (int s=0;s<DS;++s){
      float a = __expf(dtv*Av[s]);
      Pv[s] *= a;
      h[s] = a*h[s] + dtx*bm_l[t][s];
    }
  }
  const int base = ((b*DI + i)*NCH + ch)*DS;
  #pragma unroll
  for (int s4=0;s4<4;++s4){
    *(float4*)&P[base+s4*4] = make_float4(Pv[s4*4+0],Pv[s4*4+1],Pv[s4*4+2],Pv[s4*4+3]);
    *(float4*)&Q[base+s4*4] = make_float4(h[s4*4+0],h[s4*4+1],h[s4*4+2],h[s4*4+3]);
  }
}

// ---------------- scan phase 2: sequential prefix over chunks (tiny)
__global__ __launch_bounds__(256) void k_scan2(const float* __restrict__ P, const float* __restrict__ Q,
                                               float* __restrict__ Hin){
  int tid = blockIdx.x*256 + threadIdx.x;   // B*DI*DS = 12288
  int s = tid & 15; int ci = tid >> 4;
  float h = 0.f;
  for (int ch=0; ch<NCH; ++ch){
    int idx = (ci*NCH+ch)*DS + s;
    Hin[idx] = h;
    h = P[idx]*h + Q[idx];
  }
}

// ---------------- scan phase 3: states in registers, emit y bf16
__global__ __launch_bounds__(128) void k_scan3(const float* __restrict__ dt,
    const float* __restrict__ xi, const float* __restrict__ Bm, const float* __restrict__ Cm,
    const u16* __restrict__ zz_b, const u16* __restrict__ A_log, const u16* __restrict__ Dp,
    const float* __restrict__ Hin, u16* __restrict__ Y){
  const int tid = threadIdx.x;
  const int i = blockIdx.x*128 + tid;
  const int ch = blockIdx.y, b = blockIdx.z;
  __shared__ float bm_l[CL][DS], cm_l[CL][DS];
  {
    int r = tid>>2, c4 = (tid&3)*4;
    *(float4*)&bm_l[r][c4] = *(const float4*)&Bm[(b*NN + ch*CL + r)*DS + c4];
    *(float4*)&cm_l[r][c4] = *(const float4*)&Cm[(b*NN + ch*CL + r)*DS + c4];
  }
  float Av[DS];
  {
    u16x8 a0 = *(const u16x8*)(A_log + i*DS);
    u16x8 a1 = *(const u16x8*)(A_log + i*DS + 8);
    #pragma unroll
    for (int s=0;s<8;++s){ Av[s] = -__expf(bf(a0[s])); Av[8+s] = -__expf(bf(a1[s])); }
  }
  const float Dv = bf(Dp[i]);
  float h[DS];
  const int base = ((b*DI + i)*NCH + ch)*DS;
  #pragma unroll
  for (int s4=0;s4<4;++s4){
    float4 hv = *(const float4*)&Hin[base+s4*4];
    h[s4*4+0]=hv.x; h[s4*4+1]=hv.y; h[s4*4+2]=hv.z; h[s4*4+3]=hv.w;
  }
  __syncthreads();
  const int nb = b*NN + ch*CL;
  #pragma unroll 4
  for (int t=0;t<CL;++t){
    float dtv = dt[(nb+t)*DI + i];
    float xv  = xi[(nb+t)*DI + i];
    float zv  = bf(zz_b[(nb+t)*DI + i]);
    float dtx = dtv*xv;
    float y = 0.f;
    #pragma unroll
    for (int s=0;s<DS;++s){
      float a = __expf(dtv*Av[s]);
      h[s] = a*h[s] + dtx*bm_l[t][s];
      y += h[s]*cm_l[t][s];
    }
    y += Dv*xv;
    y *= zv/(1.f+__expf(-zv));
    Y[(nb+t)*DI + i] = f2bf(y);
  }
}

// ---------------- MFMA out GEMM + residual: seq += Y[8192x384] x out_w[192x384]^T
__global__ __launch_bounds__(256) void k_out(const u16* __restrict__ Y,
    const u16* __restrict__ out_w, float* __restrict__ seq){
  const int tid = threadIdx.x;
  const int m0 = blockIdx.x*64;
  const int d0 = blockIdx.y*64;
  __shared__ u16 aL[64][200];
  __shared__ u16 bL[64][200];
  const int w = tid >> 6, lane = tid & 63;
  const int lm = lane & 15, lk = lane >> 4;
  f32x4 acc[4];
  #pragma unroll
  for (int i=0;i<4;++i) acc[i] = (f32x4){0.f,0.f,0.f,0.f};
  for (int c=0; c<2; ++c){
    const int kc = c*192;
    for (int idx = tid*8; idx < 64*192; idx += 2048){
      int row = idx/192, col = idx%192;
      *(u16x8*)&aL[row][col] = *(const u16x8*)(Y     + (m0+row)*DI + kc + col);
      *(u16x8*)&bL[row][col] = *(const u16x8*)(out_w + (d0+row)*DI + kc + col);
    }
    __syncthreads();
    #pragma unroll
    for (int ks=0; ks<6; ++ks){
      s16x8 a = *(s16x8*)&aL[w*16 + lm][ks*32 + lk*8];
      #pragma unroll
      for (int nt=0; nt<4; ++nt){
        s16x8 b = *(s16x8*)&bL[nt*16 + lm][ks*32 + lk*8];
        acc[nt] = __builtin_amdgcn_mfma_f32_16x16x32_bf16(a, b, acc[nt], 0, 0, 0);
      }
    }
    __syncthreads();
  }
  #pragma unroll
  for (int nt=0; nt<4; ++nt){
    int d = d0 + nt*16 + lm;
    #pragma unroll
    for (int r=0; r<4; ++r){
      int tok = m0 + w*16 + lk*4 + r;
      seq[tok*DD + d] += acc[nt][r];
    }
  }
}

// ---------------- final rmsnorm + transpose to (B,D,H,W); dtype per flag
__global__ __launch_bounds__(192) void k_final(const float* __restrict__ seq,
    const u16* __restrict__ normf_w, void* __restrict__ out, const int* __restrict__ flag){
  const int d = threadIdx.x;
  const int bn = blockIdx.x;
  const int b = bn >> 12, n = bn & (NN-1);
  __shared__ float wred[3];
  float v = seq[bn*DD + d];
  float s = v*v;
  #pragma unroll
  for (int off=32; off>=1; off>>=1) s += __shfl_down(s,off);
  if ((d&63)==0) wred[d>>6]=s;
  __syncthreads();
  float r = rsqrtf((wred[0]+wred[1]+wred[2])*(1.f/DD) + EPSF);
  float res = v * r * bf(normf_w[d]);
  int o = (b*DD+d)*NN + n;
  if (*flag) ((float*)out)[o] = res;
  else       ((u16*)out)[o]   = f2bf(res);
}

extern "C" void kernel_launch(void* const* d_in, const int* in_sizes, int n_in,
                              void* d_out, int out_size, void* d_ws, size_t ws_size,
                              hipStream_t stream){
  Ptrs ps;
  for (int i=0;i<16;++i) ps.p[i] = d_in[i];

  u16* arena = (u16*)d_ws;
  int* flag  = (int*)(arena + ARENA_TOTAL);
  float* fbase = (float*)((char*)d_ws + ARENA_BYTES);

  float* seq  = fbase;                 // NT*DD
  float* xi   = seq  + NT*DD;          // NT*DI
  float* dt   = xi   + NT*DI;          // NT*DI
  float* Bm   = dt   + NT*DI;          // NT*DS
  float* Cm   = Bm   + NT*DS;          // NT*DS
  float* Hin  = Cm   + NT*DS;          // BB*DI*NCH*DS = 1.57M floats
  u16* xn_b   = (u16*)(Hin + BB*DI*NCH*DS);  // NT*DD u16
  u16* xi_c   = xn_b + NT*DD;          // NT*DI u16
  u16* zz_b   = xi_c + NT*DI;          // NT*DI u16
  u16* Y_b    = zz_b + NT*DI;          // NT*DI u16
  // P/Q alias dead regions during the scan phases:
  //   Pb <- Y_b  (Y dead until scan3 writes it; scan2 consumes Pb before that)
  //   Qb <- xi_c (xi_c dead after k_conv_proj)
  float* Pb   = (float*)Y_b;           // BB*DI*NCH*DS = NT*DI/2 floats ✓ fits
  float* Qb   = (float*)xi_c;

  const u16* xA      = arena + OFF_X;
  const u16* proj_w  = arena + OFF_PROJ_W;
  const u16* proj_b  = arena + OFF_PROJ_B;
  const u16* lp_w    = arena + OFF_LP_W;
  const u16* lp_b    = arena + OFF_LP_B;
  const u16* norm_w  = arena + OFF_NORM_W;
  const u16* in_w    = arena + OFF_IN_W;
  const u16* conv_w  = arena + OFF_CONV_W;
  const u16* conv_b  = arena + OFF_CONV_B;
  const u16* xproj_w = arena + OFF_XPROJ_W;
  const u16* dt_w    = arena + OFF_DT_W;
  const u16* dt_b    = arena + OFF_DT_B;
  const u16* A_log   = arena + OFF_A_LOG;
  const u16* Dp      = arena + OFF_DP;
  const u16* out_w   = arena + OFF_OUT_W;
  const u16* normf_w = arena + OFF_NORMF_W;

  k_detect<<<1, 256, 0, stream>>>((const u16*)d_in[0], flag);
  k_cvt<<<(ARENA_TOTAL+255)/256, 256, 0, stream>>>(ps, flag, arena);

  k_proj<<<(NT*DD+255)/256, 256, 0, stream>>>(xA, proj_w, proj_b, seq);
  for (int l=0; l<DEPTH; ++l){
    k_lp_norm<<<NT/32, 256, 0, stream>>>(seq, lp_w + l*DD*2*DD, lp_b + l*DD, norm_w + l*DD, xn_b);
    k_inproj<<<dim3(NT/64, 12), 256, 0, stream>>>(xn_b, in_w + l*2*DI*DD, xi_c, zz_b);
    k_conv_proj<<<NT/8, 256, 0, stream>>>(xi_c, conv_w + l*DI*DC, conv_b + l*DI,
        xproj_w + l*(DTR+2*DS)*DI, dt_w + l*DI*DTR, dt_b + l*DI, xi, dt, Bm, Cm);
    k_scan1<<<dim3(DI/128, NCH, BB), 128, 0, stream>>>(dt, xi, Bm, A_log + l*DI*DS, Pb, Qb);
    k_scan2<<<(BB*DI*DS)/256, 256, 0, stream>>>(Pb, Qb, Hin);
    k_scan3<<<dim3(DI/128, NCH, BB), 128, 0, stream>>>(dt, xi, Bm, Cm, zz_b, A_log + l*DI*DS, Dp + l*DI, Hin, Y_b);
    k_out<<<dim3(NT/64, 3), 256, 0, stream>>>(Y_b, out_w + l*DD*DI, seq);
  }
  k_final<<<NT, 192, 0, stream>>>(seq, normf_w, d_out, flag);
}

// Round 6
// 613.111 us; speedup vs baseline: 2.6073x; 1.1375x over previous
//
#include <hip/hip_runtime.h>
#include <hip/hip_bf16.h>

#define BB 2
#define NN 4096
#define DD 192
#define DI 384
#define DS 16
#define DTR 12
#define DC 4
#define DEPTH 4
#define NT (BB*NN)
#define NCH 128
#define CL 32
#define EPSF 1e-5f

// arena element offsets (u16 units)
#define OFF_X       0
#define OFF_PROJ_W  24576
#define OFF_PROJ_B  25152
#define OFF_LP_W    25344
#define OFF_LP_B    320256
#define OFF_NORM_W  321024
#define OFF_IN_W    321792
#define OFF_CONV_W  911616
#define OFF_CONV_B  917760
#define OFF_XPROJ_W 919296
#define OFF_DT_W    986880
#define OFF_DT_B    1005312
#define OFF_A_LOG   1006848
#define OFF_DP      1031424
#define OFF_OUT_W   1032960
#define OFF_NORMF_W 1327872
#define ARENA_TOTAL 1328064
#define ARENA_BYTES 2656160   // ARENA_TOTAL*2 + 32 pad (16B aligned)

typedef __hip_bfloat16 bf16_t;
typedef unsigned short u16;
typedef unsigned int u32;
typedef __attribute__((ext_vector_type(8))) unsigned short u16x8;
typedef __attribute__((ext_vector_type(8))) short s16x8;
typedef __attribute__((ext_vector_type(4))) float f32x4;

struct Ptrs { const void* p[16]; };

__device__ __forceinline__ float bf(u16 v){ return __uint_as_float(((u32)v)<<16); }
__device__ __forceinline__ u16 f2bf(float f){
  u32 b = __float_as_uint(f);
  return (u16)((b + 0x7FFFu + ((b>>16)&1u)) >> 16);
}

// ---------------- dtype detector: are inputs bf16(u16) or f32 storage?
__global__ __launch_bounds__(256) void k_detect(const u16* __restrict__ x, int* flag){
  __shared__ int cnt;
  if (threadIdx.x==0) cnt=0;
  __syncthreads();
  u32 v = x[2*threadIdx.x];
  int ex = (int)((v>>7)&0xFF);
  if (ex>=100 && ex<=140) atomicAdd(&cnt,1);
  __syncthreads();
  if (threadIdx.x==0) *flag = (cnt>128) ? 0 : 1;   // 0 = bf16 storage, 1 = f32 storage
}

// ---------------- canonicalize all inputs into bf16 arena
__global__ __launch_bounds__(256) void k_cvt(Ptrs ps, const int* __restrict__ flag, u16* __restrict__ arena){
  int e = blockIdx.x*256 + threadIdx.x;
  if (e >= ARENA_TOTAL) return;
  const void* sp; int off;
  if      (e < OFF_PROJ_W ){ sp=ps.p[0];  off=OFF_X; }
  else if (e < OFF_PROJ_B ){ sp=ps.p[1];  off=OFF_PROJ_W; }
  else if (e < OFF_LP_W   ){ sp=ps.p[2];  off=OFF_PROJ_B; }
  else if (e < OFF_LP_B   ){ sp=ps.p[3];  off=OFF_LP_W; }
  else if (e < OFF_NORM_W ){ sp=ps.p[4];  off=OFF_LP_B; }
  else if (e < OFF_IN_W   ){ sp=ps.p[5];  off=OFF_NORM_W; }
  else if (e < OFF_CONV_W ){ sp=ps.p[6];  off=OFF_IN_W; }
  else if (e < OFF_CONV_B ){ sp=ps.p[7];  off=OFF_CONV_W; }
  else if (e < OFF_XPROJ_W){ sp=ps.p[8];  off=OFF_CONV_B; }
  else if (e < OFF_DT_W   ){ sp=ps.p[9];  off=OFF_XPROJ_W; }
  else if (e < OFF_DT_B   ){ sp=ps.p[10]; off=OFF_DT_W; }
  else if (e < OFF_A_LOG  ){ sp=ps.p[11]; off=OFF_DT_B; }
  else if (e < OFF_DP     ){ sp=ps.p[12]; off=OFF_A_LOG; }
  else if (e < OFF_OUT_W  ){ sp=ps.p[13]; off=OFF_DP; }
  else if (e < OFF_NORMF_W){ sp=ps.p[14]; off=OFF_OUT_W; }
  else                     { sp=ps.p[15]; off=OFF_NORMF_W; }
  int k = e - off;
  if (*flag){
    u32 v = ((const u32*)sp)[k];
    arena[e] = (u16)((v + 0x7FFFu + ((v>>16)&1u)) >> 16);
  } else {
    arena[e] = ((const u16*)sp)[k];
  }
}

// ---------------- initial projection: seq[b,n,d] = sum_c x[b,c,n]*pw[d,c] + pb[d]
__global__ __launch_bounds__(256) void k_proj(const u16* __restrict__ x, const u16* __restrict__ pw,
                                              const u16* __restrict__ pb, float* __restrict__ seq){
  int idx = blockIdx.x*256 + threadIdx.x;
  if (idx >= NT*DD) return;
  int d = idx % DD; int bn = idx / DD; int b = bn >> 12; int n = bn & (NN-1);
  float acc = bf(pb[d]);
  acc += bf(x[(b*3+0)*NN + n]) * bf(pw[d*3+0]);
  acc += bf(x[(b*3+1)*NN + n]) * bf(pw[d*3+1]);
  acc += bf(x[(b*3+2)*NN + n]) * bf(pw[d*3+2]);
  seq[idx] = acc;
}

// ---------------- MFMA: shift+concat + lp GEMM + bias + rmsnorm -> xn (bf16)
__global__ __launch_bounds__(256) void k_lp_norm(const float* __restrict__ seq,
    const u16* __restrict__ lp_w, const u16* __restrict__ lp_b, const u16* __restrict__ norm_w,
    u16* __restrict__ xn){
  const int tid = threadIdx.x;
  const int n0 = blockIdx.x*32;
  __shared__ u16 combL[32][392];     // 384 + 8 pad
  __shared__ u16 wL[192][136];       // 128 + 8 pad
  __shared__ float accL[32][200];    // 192 + 8 pad
  __shared__ float ssq[32];

  for (int idx = tid*4; idx < 32*DD; idx += 1024){
    int t = idx/DD, d = idx%DD;
    int gn = n0 + t;
    float4 cur = *(const float4*)&seq[gn*DD + d];
    float4 prv = make_float4(0.f,0.f,0.f,0.f);
    if ((gn & (NN-1)) != 0) prv = *(const float4*)&seq[(gn-1)*DD + d];
    combL[t][d+0]=f2bf(cur.x); combL[t][d+1]=f2bf(cur.y); combL[t][d+2]=f2bf(cur.z); combL[t][d+3]=f2bf(cur.w);
    combL[t][DD+d+0]=f2bf(cur.x-prv.x); combL[t][DD+d+1]=f2bf(cur.y-prv.y);
    combL[t][DD+d+2]=f2bf(cur.z-prv.z); combL[t][DD+d+3]=f2bf(cur.w-prv.w);
  }

  const int w = tid >> 6;
  const int lane = tid & 63;
  const int lm = lane & 15, lk = lane >> 4;
  const int mt = w & 1;
  const int nbase = (w >> 1)*6;

  f32x4 acc[6];
  #pragma unroll
  for (int i=0;i<6;++i) acc[i] = (f32x4){0.f,0.f,0.f,0.f};

  for (int c=0;c<3;++c){
    const int kc = c*128;
    for (int idx = tid*8; idx < 192*128; idx += 2048){
      int row = idx >> 7, col = idx & 127;
      *(u16x8*)&wL[row][col] = *(const u16x8*)(lp_w + row*384 + kc + col);
    }
    __syncthreads();
    #pragma unroll
    for (int ks=0; ks<4; ++ks){
      s16x8 a = *(s16x8*)&combL[mt*16 + lm][kc + ks*32 + lk*8];
      #pragma unroll
      for (int nt=0; nt<6; ++nt){
        s16x8 b = *(s16x8*)&wL[(nbase+nt)*16 + lm][ks*32 + lk*8];
        acc[nt] = __builtin_amdgcn_mfma_f32_16x16x32_bf16(a, b, acc[nt], 0, 0, 0);
      }
    }
    __syncthreads();
  }
  #pragma unroll
  for (int nt=0; nt<6; ++nt){
    #pragma unroll
    for (int r=0; r<4; ++r){
      int m = mt*16 + lk*4 + r;
      int n = (nbase+nt)*16 + lm;
      accL[m][n] = acc[nt][r] + bf(lp_b[n]);
    }
  }
  __syncthreads();
  {
    int tok = tid >> 3, j = tid & 7;
    float s = 0.f;
    #pragma unroll
    for (int c=0;c<24;++c){ float v = accL[tok][j*24+c]; s += v*v; }
    s += __shfl_xor(s,1); s += __shfl_xor(s,2); s += __shfl_xor(s,4);
    if (j==0) ssq[tok] = rsqrtf(s*(1.f/DD) + EPSF);
  }
  __syncthreads();
  for (int idx = tid; idx < 32*DD; idx += 256){
    int t = idx/DD, d = idx%DD;
    xn[(n0+t)*DD + d] = f2bf(accL[t][d] * ssq[t] * bf(norm_w[d]));
  }
}

// ---------------- MFMA in_w GEMM: [8192x768] = xn[8192x192] x in_w[768x192]^T
__global__ __launch_bounds__(256) void k_inproj(const u16* __restrict__ xn,
    const u16* __restrict__ in_w, u16* __restrict__ xi_c, u16* __restrict__ zz_b){
  const int tid = threadIdx.x;
  const int m0 = blockIdx.x*64;
  const int e0 = blockIdx.y*64;
  __shared__ u16 aL[64][200];
  __shared__ u16 bL[64][200];
  for (int idx = tid*8; idx < 64*192; idx += 2048){
    int row = idx/192, col = idx%192;
    *(u16x8*)&aL[row][col] = *(const u16x8*)(xn   + (m0+row)*192 + col);
    *(u16x8*)&bL[row][col] = *(const u16x8*)(in_w + (e0+row)*192 + col);
  }
  __syncthreads();
  const int w = tid >> 6, lane = tid & 63;
  const int lm = lane & 15, lk = lane >> 4;
  f32x4 acc[4];
  #pragma unroll
  for (int i=0;i<4;++i) acc[i] = (f32x4){0.f,0.f,0.f,0.f};
  #pragma unroll
  for (int ks=0; ks<6; ++ks){
    s16x8 a = *(s16x8*)&aL[w*16 + lm][ks*32 + lk*8];
    #pragma unroll
    for (int nt=0; nt<4; ++nt){
      s16x8 b = *(s16x8*)&bL[nt*16 + lm][ks*32 + lk*8];
      acc[nt] = __builtin_amdgcn_mfma_f32_16x16x32_bf16(a, b, acc[nt], 0, 0, 0);
    }
  }
  #pragma unroll
  for (int nt=0; nt<4; ++nt){
    int e = e0 + nt*16 + lm;
    #pragma unroll
    for (int r=0; r<4; ++r){
      int tok = m0 + w*16 + lk*4 + r;
      u16 v = f2bf(acc[nt][r]);
      if (e0 < DI) xi_c[tok*DI + e]      = v;
      else         zz_b[tok*DI + e - DI] = v;
    }
  }
}

// ---------------- causal conv(k=4) + silu: xi_c -> xc (bf16) + xi (f32)
// 4 tokens per thread (halo reuse), coalesced in channel i.
__global__ __launch_bounds__(256) void k_conv(const u16* __restrict__ xi_c,
    const u16* __restrict__ conv_w, const u16* __restrict__ conv_b,
    u16* __restrict__ xc_b, float* __restrict__ xi){
  int idx = blockIdx.x*256 + threadIdx.x;       // over (NT/4)*DI
  int i = idx % DI; int bg = idx / DI;
  int nstart = bg*4;
  int base = nstart & ~(NN-1);
  float w0 = bf(conv_w[i*4+0]), w1 = bf(conv_w[i*4+1]), w2 = bf(conv_w[i*4+2]), w3 = bf(conv_w[i*4+3]);
  float cb = bf(conv_b[i]);
  float xv[7];
  #pragma unroll
  for (int t=0; t<3; ++t){
    int bn2 = nstart - 3 + t;
    xv[t] = (bn2 >= base) ? bf(xi_c[bn2*DI + i]) : 0.f;
  }
  #pragma unroll
  for (int t=3; t<7; ++t) xv[t] = bf(xi_c[(nstart + t - 3)*DI + i]);
  #pragma unroll
  for (int t=0; t<4; ++t){
    float acc = cb + xv[t]*w0 + xv[t+1]*w1 + xv[t+2]*w2 + xv[t+3]*w3;
    float v = acc/(1.f+__expf(-acc));
    int o = (nstart+t)*DI + i;
    xc_b[o] = f2bf(v);
    xi[o] = v;
  }
}

// ---------------- MFMA xproj (44x384) + dt GEMM (384x12) + softplus
// 32 tokens/block, 4 waves: (mt = w&1, n-half = w>>1)
__global__ __launch_bounds__(256) void k_xproj_dt(const u16* __restrict__ xc,
    const u16* __restrict__ xproj_w, const u16* __restrict__ dt_w, const u16* __restrict__ dt_bv,
    float* __restrict__ dt_o, float* __restrict__ Bm, float* __restrict__ Cm){
  const int tid = threadIdx.x;
  const int n0 = blockIdx.x*32;
  __shared__ u16 xcL[32][392];       // 384 + 8 pad
  __shared__ u16 dtwL[384][24];      // 12 real + 12 zero pad (K-pad to 32 handled by lk guard)
  __shared__ float dbcL[32][16];     // dbc[:,0:12] + 4 zero cols
  for (int idx=tid; idx<512; idx+=256) ((float*)dbcL)[idx]=0.f;
  for (int idx=tid*8; idx<32*384; idx+=2048){
    int r=idx/384, c=idx%384;
    *(u16x8*)&xcL[r][c] = *(const u16x8*)(xc + (n0+r)*DI + c);
  }
  for (int idx=tid; idx<384*12; idx+=256){
    int r=idx/12, c=idx%12;
    dtwL[r][c] = dt_w[idx];
    dtwL[r][12+c] = 0;
  }
  __syncthreads();
  const int w = tid>>6, lane = tid&63, lm = lane&15, lk = lane>>4;
  const int mt = w & 1, nh = w >> 1;
  const s16x8 zb = {0,0,0,0,0,0,0,0};
  if (nh == 0){
    f32x4 acc0 = {0.f,0.f,0.f,0.f}, acc1 = {0.f,0.f,0.f,0.f};
    #pragma unroll
    for (int ks=0; ks<12; ++ks){
      s16x8 a = *(s16x8*)&xcL[mt*16+lm][ks*32+lk*8];
      s16x8 b0 = *(const s16x8*)(xproj_w + lm*384 + ks*32 + lk*8);
      s16x8 b1 = *(const s16x8*)(xproj_w + (16+lm)*384 + ks*32 + lk*8);
      acc0 = __builtin_amdgcn_mfma_f32_16x16x32_bf16(a, b0, acc0, 0, 0, 0);
      acc1 = __builtin_amdgcn_mfma_f32_16x16x32_bf16(a, b1, acc1, 0, 0, 0);
    }
    #pragma unroll
    for (int r=0;r<4;++r){
      int m = mt*16 + lk*4 + r;
      int gm = n0 + m;
      if (lm < 12) dbcL[m][lm] = acc0[r];
      else         Bm[gm*DS + lm-12] = acc0[r];
      int e1 = 16+lm;
      if (e1 < 28) Bm[gm*DS + e1-12] = acc1[r];
      else         Cm[gm*DS + e1-28] = acc1[r];
    }
  } else {
    f32x4 acc2 = {0.f,0.f,0.f,0.f};
    #pragma unroll
    for (int ks=0; ks<12; ++ks){
      s16x8 a = *(s16x8*)&xcL[mt*16+lm][ks*32+lk*8];
      s16x8 b2 = (lm<12) ? *(const s16x8*)(xproj_w + (32+lm)*384 + ks*32 + lk*8) : zb;
      acc2 = __builtin_amdgcn_mfma_f32_16x16x32_bf16(a, b2, acc2, 0, 0, 0);
    }
    #pragma unroll
    for (int r=0;r<4;++r){
      int m = mt*16 + lk*4 + r;
      int e2 = 32+lm;
      if (e2 < 44) Cm[(n0+m)*DS + e2-28] = acc2[r];
    }
  }
  __syncthreads();
  // dt GEMM: out[32 tok][384] = dbc[32][12 pad 32] x dt_w[384][12 pad 32]^T
  s16x8 a_dt = zb;
  if (lk < 2){
    #pragma unroll
    for (int j=0;j<8;++j) a_dt[j] = (short)f2bf(dbcL[mt*16+lm][lk*8+j]);
  }
  #pragma unroll
  for (int q=0;q<12;++q){
    int nt = nh*12 + q;
    s16x8 b = (lk<2) ? *(s16x8*)&dtwL[nt*16+lm][lk*8] : zb;
    f32x4 acc = {0.f,0.f,0.f,0.f};
    acc = __builtin_amdgcn_mfma_f32_16x16x32_bf16(a_dt, b, acc, 0, 0, 0);
    int i = nt*16 + lm;
    float bias = bf(dt_bv[i]);
    #pragma unroll
    for (int r=0;r<4;++r){
      int m = mt*16 + lk*4 + r;
      float xval = acc[r] + bias;
      float sp = (xval>20.f)? xval : log1pf(__expf(xval));
      dt_o[(n0+m)*DI + i] = sp;
    }
  }
}

// ---------------- scan phase 1: per-chunk local scan, states in registers -> P, Q
__global__ __launch_bounds__(128) void k_scan1(const float* __restrict__ dt,
    const float* __restrict__ xi, const float* __restrict__ Bm,
    const u16* __restrict__ A_log, float* __restrict__ P, float* __restrict__ Q){
  const int tid = threadIdx.x;
  const int i = blockIdx.x*128 + tid;
  const int ch = blockIdx.y, b = blockIdx.z;
  __shared__ float bm_l[CL][DS];
  {
    int r = tid>>2, c4 = (tid&3)*4;
    *(float4*)&bm_l[r][c4] = *(const float4*)&Bm[(b*NN + ch*CL + r)*DS + c4];
  }
  float Av[DS];
  {
    u16x8 a0 = *(const u16x8*)(A_log + i*DS);
    u16x8 a1 = *(const u16x8*)(A_log + i*DS + 8);
    #pragma unroll
    for (int s=0;s<8;++s){ Av[s] = -__expf(bf(a0[s])); Av[8+s] = -__expf(bf(a1[s])); }
  }
  __syncthreads();
  float Pv[DS], h[DS];
  #pragma unroll
  for (int s=0;s<DS;++s){ Pv[s]=1.f; h[s]=0.f; }
  const int nb = b*NN + ch*CL;
  #pragma unroll 4
  for (int t=0;t<CL;++t){
    float dtv = dt[(nb+t)*DI + i];
    float xv  = xi[(nb+t)*DI + i];
    float dtx = dtv*xv;
    #pragma unroll
    for (int s=0;s<DS;++s){
      float a = __expf(dtv*Av[s]);
      Pv[s] *= a;
      h[s] = a*h[s] + dtx*bm_l[t][s];
    }
  }
  const int base = ((b*DI + i)*NCH + ch)*DS;
  #pragma unroll
  for (int s4=0;s4<4;++s4){
    *(float4*)&P[base+s4*4] = make_float4(Pv[s4*4+0],Pv[s4*4+1],Pv[s4*4+2],Pv[s4*4+3]);
    *(float4*)&Q[base+s4*4] = make_float4(h[s4*4+0],h[s4*4+1],h[s4*4+2],h[s4*4+3]);
  }
}

// ---------------- scan phase 2: sequential prefix over chunks (tiny)
__global__ __launch_bounds__(256) void k_scan2(const float* __restrict__ P, const float* __restrict__ Q,
                                               float* __restrict__ Hin){
  int tid = blockIdx.x*256 + threadIdx.x;   // B*DI*DS = 12288
  int s = tid & 15; int ci = tid >> 4;
  float h = 0.f;
  for (int ch=0; ch<NCH; ++ch){
    int idx = (ci*NCH+ch)*DS + s;
    Hin[idx] = h;
    h = P[idx]*h + Q[idx];
  }
}

// ---------------- scan phase 3: states in registers, emit y bf16
__global__ __launch_bounds__(128) void k_scan3(const float* __restrict__ dt,
    const float* __restrict__ xi, const float* __restrict__ Bm, const float* __restrict__ Cm,
    const u16* __restrict__ zz_b, const u16* __restrict__ A_log, const u16* __restrict__ Dp,
    const float* __restrict__ Hin, u16* __restrict__ Y){
  const int tid = threadIdx.x;
  const int i = blockIdx.x*128 + tid;
  const int ch = blockIdx.y, b = blockIdx.z;
  __shared__ float bm_l[CL][DS], cm_l[CL][DS];
  {
    int r = tid>>2, c4 = (tid&3)*4;
    *(float4*)&bm_l[r][c4] = *(const float4*)&Bm[(b*NN + ch*CL + r)*DS + c4];
    *(float4*)&cm_l[r][c4] = *(const float4*)&Cm[(b*NN + ch*CL + r)*DS + c4];
  }
  float Av[DS];
  {
    u16x8 a0 = *(const u16x8*)(A_log + i*DS);
    u16x8 a1 = *(const u16x8*)(A_log + i*DS + 8);
    #pragma unroll
    for (int s=0;s<8;++s){ Av[s] = -__expf(bf(a0[s])); Av[8+s] = -__expf(bf(a1[s])); }
  }
  const float Dv = bf(Dp[i]);
  float h[DS];
  const int base = ((b*DI + i)*NCH + ch)*DS;
  #pragma unroll
  for (int s4=0;s4<4;++s4){
    float4 hv = *(const float4*)&Hin[base+s4*4];
    h[s4*4+0]=hv.x; h[s4*4+1]=hv.y; h[s4*4+2]=hv.z; h[s4*4+3]=hv.w;
  }
  __syncthreads();
  const int nb = b*NN + ch*CL;
  #pragma unroll 4
  for (int t=0;t<CL;++t){
    float dtv = dt[(nb+t)*DI + i];
    float xv  = xi[(nb+t)*DI + i];
    float zv  = bf(zz_b[(nb+t)*DI + i]);
    float dtx = dtv*xv;
    float y = 0.f;
    #pragma unroll
    for (int s=0;s<DS;++s){
      float a = __expf(dtv*Av[s]);
      h[s] = a*h[s] + dtx*bm_l[t][s];
      y += h[s]*cm_l[t][s];
    }
    y += Dv*xv;
    y *= zv/(1.f+__expf(-zv));
    Y[(nb+t)*DI + i] = f2bf(y);
  }
}

// ---------------- MFMA out GEMM + residual: seq += Y[8192x384] x out_w[192x384]^T
__global__ __launch_bounds__(256) void k_out(const u16* __restrict__ Y,
    const u16* __restrict__ out_w, float* __restrict__ seq){
  const int tid = threadIdx.x;
  const int m0 = blockIdx.x*64;
  const int d0 = blockIdx.y*64;
  __shared__ u16 aL[64][200];
  __shared__ u16 bL[64][200];
  const int w = tid >> 6, lane = tid & 63;
  const int lm = lane & 15, lk = lane >> 4;
  f32x4 acc[4];
  #pragma unroll
  for (int i=0;i<4;++i) acc[i] = (f32x4){0.f,0.f,0.f,0.f};
  for (int c=0; c<2; ++c){
    const int kc = c*192;
    for (int idx = tid*8; idx < 64*192; idx += 2048){
      int row = idx/192, col = idx%192;
      *(u16x8*)&aL[row][col] = *(const u16x8*)(Y     + (m0+row)*DI + kc + col);
      *(u16x8*)&bL[row][col] = *(const u16x8*)(out_w + (d0+row)*DI + kc + col);
    }
    __syncthreads();
    #pragma unroll
    for (int ks=0; ks<6; ++ks){
      s16x8 a = *(s16x8*)&aL[w*16 + lm][ks*32 + lk*8];
      #pragma unroll
      for (int nt=0; nt<4; ++nt){
        s16x8 b = *(s16x8*)&bL[nt*16 + lm][ks*32 + lk*8];
        acc[nt] = __builtin_amdgcn_mfma_f32_16x16x32_bf16(a, b, acc[nt], 0, 0, 0);
      }
    }
    __syncthreads();
  }
  #pragma unroll
  for (int nt=0; nt<4; ++nt){
    int d = d0 + nt*16 + lm;
    #pragma unroll
    for (int r=0; r<4; ++r){
      int tok = m0 + w*16 + lk*4 + r;
      seq[tok*DD + d] += acc[nt][r];
    }
  }
}

// ---------------- final rmsnorm + transpose to (B,D,H,W); dtype per flag
__global__ __launch_bounds__(192) void k_final(const float* __restrict__ seq,
    const u16* __restrict__ normf_w, void* __restrict__ out, const int* __restrict__ flag){
  const int d = threadIdx.x;
  const int bn = blockIdx.x;
  const int b = bn >> 12, n = bn & (NN-1);
  __shared__ float wred[3];
  float v = seq[bn*DD + d];
  float s = v*v;
  #pragma unroll
  for (int off=32; off>=1; off>>=1) s += __shfl_down(s,off);
  if ((d&63)==0) wred[d>>6]=s;
  __syncthreads();
  float r = rsqrtf((wred[0]+wred[1]+wred[2])*(1.f/DD) + EPSF);
  float res = v * r * bf(normf_w[d]);
  int o = (b*DD+d)*NN + n;
  if (*flag) ((float*)out)[o] = res;
  else       ((u16*)out)[o]   = f2bf(res);
}

extern "C" void kernel_launch(void* const* d_in, const int* in_sizes, int n_in,
                              void* d_out, int out_size, void* d_ws, size_t ws_size,
                              hipStream_t stream){
  Ptrs ps;
  for (int i=0;i<16;++i) ps.p[i] = d_in[i];

  u16* arena = (u16*)d_ws;
  int* flag  = (int*)(arena + ARENA_TOTAL);
  float* fbase = (float*)((char*)d_ws + ARENA_BYTES);

  float* seq  = fbase;                 // NT*DD
  float* xi   = seq  + NT*DD;          // NT*DI
  float* dt   = xi   + NT*DI;          // NT*DI
  float* Bm   = dt   + NT*DI;          // NT*DS
  float* Cm   = Bm   + NT*DS;          // NT*DS
  float* Hin  = Cm   + NT*DS;          // BB*DI*NCH*DS
  u16* xn_b   = (u16*)(Hin + BB*DI*NCH*DS);  // NT*DD u16
  u16* xi_c   = xn_b + NT*DD;          // NT*DI u16
  u16* zz_b   = xi_c + NT*DI;          // NT*DI u16
  u16* Y_b    = zz_b + NT*DI;          // NT*DI u16
  // aliasing chain (all stream-ordered):
  //   xc_b = Y_b   (conv out; dead after k_xproj_dt)
  //   Pb   = Y_b   (scan1 out, overwrites xc_b; dead after scan2)
  //   Qb   = xi_c  (xi_c dead after k_conv)
  //   scan3 writes Y_b (overwrites Pb)
  u16*   xc_b = Y_b;
  float* Pb   = (float*)Y_b;
  float* Qb   = (float*)xi_c;

  const u16* xA      = arena + OFF_X;
  const u16* proj_w  = arena + OFF_PROJ_W;
  const u16* proj_b  = arena + OFF_PROJ_B;
  const u16* lp_w    = arena + OFF_LP_W;
  const u16* lp_b    = arena + OFF_LP_B;
  const u16* norm_w  = arena + OFF_NORM_W;
  const u16* in_w    = arena + OFF_IN_W;
  const u16* conv_w  = arena + OFF_CONV_W;
  const u16* conv_b  = arena + OFF_CONV_B;
  const u16* xproj_w = arena + OFF_XPROJ_W;
  const u16* dt_w    = arena + OFF_DT_W;
  const u16* dt_b    = arena + OFF_DT_B;
  const u16* A_log   = arena + OFF_A_LOG;
  const u16* Dp      = arena + OFF_DP;
  const u16* out_w   = arena + OFF_OUT_W;
  const u16* normf_w = arena + OFF_NORMF_W;

  k_detect<<<1, 256, 0, stream>>>((const u16*)d_in[0], flag);
  k_cvt<<<(ARENA_TOTAL+255)/256, 256, 0, stream>>>(ps, flag, arena);

  k_proj<<<(NT*DD+255)/256, 256, 0, stream>>>(xA, proj_w, proj_b, seq);
  for (int l=0; l<DEPTH; ++l){
    k_lp_norm<<<NT/32, 256, 0, stream>>>(seq, lp_w + l*DD*2*DD, lp_b + l*DD, norm_w + l*DD, xn_b);
    k_inproj<<<dim3(NT/64, 12), 256, 0, stream>>>(xn_b, in_w + l*2*DI*DD, xi_c, zz_b);
    k_conv<<<(NT/4)*DI/256, 256, 0, stream>>>(xi_c, conv_w + l*DI*DC, conv_b + l*DI, xc_b, xi);
    k_xproj_dt<<<NT/32, 256, 0, stream>>>(xc_b, xproj_w + l*(DTR+2*DS)*DI, dt_w + l*DI*DTR,
        dt_b + l*DI, dt, Bm, Cm);
    k_scan1<<<dim3(DI/128, NCH, BB), 128, 0, stream>>>(dt, xi, Bm, A_log + l*DI*DS, Pb, Qb);
    k_scan2<<<(BB*DI*DS)/256, 256, 0, stream>>>(Pb, Qb, Hin);
    k_scan3<<<dim3(DI/128, NCH, BB), 128, 0, stream>>>(dt, xi, Bm, Cm, zz_b, A_log + l*DI*DS, Dp + l*DI, Hin, Y_b);
    k_out<<<dim3(NT/64, 3), 256, 0, stream>>>(Y_b, out_w + l*DD*DI, seq);
  }
  k_final<<<NT, 192, 0, stream>>>(seq, normf_w, d_out, flag);
}